// Round 20
// baseline (614.631 us; speedup 1.0000x reference)
//
#include <hip/hip_runtime.h>
#include <stdint.h>

typedef unsigned short u16;
typedef __attribute__((ext_vector_type(8))) __bf16 bf16x8;
typedef __attribute__((ext_vector_type(4))) float f32x4;

#define B_TOTAL 65536
#define KF1     1056   // GEMM1 K after folding 8 small-vocab features (was 1440)

__device__ __forceinline__ u16 f2bf(float f) {
  union { float f; uint32_t u; } v; v.f = f;
  uint32_t r = v.u + 0x7fffu + ((v.u >> 16) & 1u);
  return (u16)(r >> 16);
}
__device__ __forceinline__ float bf2f(u16 h) {
  union { uint32_t u; float f; } v; v.u = ((uint32_t)h) << 16;
  return v.f;
}

__device__ __forceinline__ void gload16(const void* g, void* lds) {
  __builtin_amdgcn_global_load_lds(
      (const __attribute__((address_space(1))) uint32_t*)g,
      (__attribute__((address_space(3))) uint32_t*)lds, 16, 0, 0);
}

// Remaining K layout (7 singles + pool): seg bases in new K
__device__ __constant__ int NEWOFF[9] = {0,128,256,384,528,672,768,912,1056};
__device__ __constant__ int SEGFID[8] = {0,1,2,6,11,12,14,15};     // feature id per seg
__device__ __constant__ int SOLDX[8]  = {0,128,256,512,912,1056,1168,1312}; // orig X col base
// ebf blob offsets (all 15 tables; only remaining singles used by desc)
__device__ __constant__ int EOFF[15] = {0,32768,65536,98304,98336,98368,101728,
                                        155008,155584,157264,158160,158496,
                                        198096,203568,203600};
__device__ __constant__ int FDIMd[15] = {128,128,128,16,16,96,144,64,80,64,48,144,96,16,144};
#define EBF_TOTAL 246080
// Folded features: T[92][1024] = E_g . W1_g
__device__ __constant__ int TROWc[8] = {0,2,4,39,48,69,83,90};     // row base per folded g
__device__ __constant__ int TDIMc[8] = {16,16,96,64,80,64,48,16};
__device__ __constant__ int TOLDX[8] = {384,400,416,656,720,800,864,1152};
__device__ __constant__ int FOLDF[8] = {3,4,5,7,8,9,10,13};        // idx-array position

// ---------------- generic weight prep: f32 [K][N] -> bf16 [N][Kpad] (for W2/W3)
__global__ void wprep_kernel(const float* __restrict__ W, u16* __restrict__ Wt,
                             int K, int N, int Kpad) {
  int o = blockIdx.x * 256 + threadIdx.x;
  if (o >= N * Kpad) return;
  int k = o % Kpad;
  int n = o / Kpad;
  float v = (k < K) ? W[(size_t)k * N + n] : 0.0f;
  Wt[o] = f2bf(v);
}

// ---------------- W1 prep with K remap: f32 W1[1424][1024] -> bf16 Wt[1024][1056]
__global__ void wprep1_kernel(const float* __restrict__ W1, u16* __restrict__ Wt) {
  int o = blockIdx.x * 256 + threadIdx.x;
  if (o >= 1024 * KF1) return;
  int k = o % KF1;
  int n = o / KF1;
  int s = 0;
#pragma unroll
  for (int t = 1; t < 8; ++t) if (k >= NEWOFF[t]) s = t;
  const int loc = k - NEWOFF[s];
  float v = 0.0f;
  if (s < 7 || loc < 112) v = W1[(size_t)(SOLDX[s] + loc) * 1024 + n];
  Wt[o] = f2bf(v);
}

// ---------------- embedding table convert: 15 f32 tables -> one bf16 blob
struct EcvtArgs { const float* E[15]; };
__global__ void ecvt_kernel(EcvtArgs p, u16* __restrict__ ebf) {
  int i = blockIdx.x * 256 + threadIdx.x;
  if (i >= EBF_TOTAL) return;
  int f = 0;
#pragma unroll
  for (int t = 1; t < 15; ++t) if (i >= EOFF[t]) f = t;
  ebf[i] = f2bf(p.E[f][i - EOFF[f]]);
}

// ---------------- tprep: T[92][1024] bf16; T[TROW[g]+v][n] = sum_d E_g[v][d]*W1[TOLDX[g]+d][n]
struct TprepArgs { const float* E[8]; };
__global__ void tprep_kernel(TprepArgs p, const float* __restrict__ W1,
                             u16* __restrict__ T) {
  int o = blockIdx.x * 256 + threadIdx.x;
  if (o >= 92 * 1024) return;
  const int n = o & 1023, rr = o >> 10;
  int g = 0;
#pragma unroll
  for (int t = 1; t < 8; ++t) if (rr >= TROWc[t]) g = t;
  const int v = rr - TROWc[g];
  const int dim = TDIMc[g];
  const float* e = p.E[g] + (size_t)v * dim;
  const float* w = W1 + (size_t)TOLDX[g] * 1024 + n;
  float s = 0.f;
  for (int d = 0; d < dim; ++d) s += e[d] * w[(size_t)d * 1024];
  T[o] = f2bf(s);
}

// ---------------- pool: userids mean over 50 -> P[Bc][144] bf16 (cols 112..143 = 0)
__global__ __launch_bounds__(512) void pool_kernel(const int* __restrict__ idx_u,
                                                   const float* __restrict__ E_u,
                                                   u16* __restrict__ P, int row_base) {
  __shared__ float eu_t[69 * 112];
  const int tid = threadIdx.x;
  {
    const float4* s4 = reinterpret_cast<const float4*>(E_u);
    float4* d4 = reinterpret_cast<float4*>(eu_t);
    for (int i = tid; i < 69 * 28; i += 512) d4[i] = s4[i];
  }
  const int lane = tid & 63;
  const int wv   = tid >> 6;
  const int row0 = blockIdx.x * 16 + wv * 2;

  const int* iu0 = idx_u + (size_t)(row_base + row0) * 50;
  const int myid0 = (lane < 50) ? iu0[lane] : 0;
  const int myid1 = (lane < 50) ? iu0[50 + lane] : 0;
  __syncthreads();

  const int half = lane >> 5;
  const int c    = lane & 31;

  auto POOL = [&](int myid, u16* prow) {
    if (c < 28) {
      float4 s = {0.f, 0.f, 0.f, 0.f};
      const float* eu = eu_t + c * 4;
      const int j0 = half * 25;
#pragma unroll
      for (int jb = 0; jb < 25; jb += 5) {
        float4 v0, v1, v2, v3, v4;
        {
          const int i0 = __shfl(myid, j0 + jb + 0);
          const int i1 = __shfl(myid, j0 + jb + 1);
          const int i2 = __shfl(myid, j0 + jb + 2);
          const int i3 = __shfl(myid, j0 + jb + 3);
          const int i4 = __shfl(myid, j0 + jb + 4);
          v0 = *reinterpret_cast<const float4*>(eu + i0 * 112);
          v1 = *reinterpret_cast<const float4*>(eu + i1 * 112);
          v2 = *reinterpret_cast<const float4*>(eu + i2 * 112);
          v3 = *reinterpret_cast<const float4*>(eu + i3 * 112);
          v4 = *reinterpret_cast<const float4*>(eu + i4 * 112);
        }
        s.x += v0.x + v1.x + v2.x + v3.x + v4.x;
        s.y += v0.y + v1.y + v2.y + v3.y + v4.y;
        s.z += v0.z + v1.z + v2.z + v3.z + v4.z;
        s.w += v0.w + v1.w + v2.w + v3.w + v4.w;
      }
      s.x += __shfl_xor(s.x, 32);
      s.y += __shfl_xor(s.y, 32);
      s.z += __shfl_xor(s.z, 32);
      s.w += __shfl_xor(s.w, 32);
      if (half == 0) {
        const float inv = 1.0f / 50.0f;
        ushort4 o;
        o.x = f2bf(s.x * inv);
        o.y = f2bf(s.y * inv);
        o.z = f2bf(s.z * inv);
        o.w = f2bf(s.w * inv);
        *reinterpret_cast<ushort4*>(prow + c * 4) = o;
      }
    } else {
      ushort4 z; z.x = 0; z.y = 0; z.z = 0; z.w = 0;
      *reinterpret_cast<ushort4*>(prow + 112 + half * 16 + (c - 28) * 4) = z;
    }
  };

  POOL(myid0, P + (size_t)row0 * 144);
  POOL(myid1, P + (size_t)(row0 + 1) * 144);
}

// ---------------- gemm1g: GEMM1 (K=1056) gather-on-stage A + folded-T epilogue
// Epilogue mm loop is unroll-1 to cap live registers (R19 regression was a
// full-unroll epilogue spilling ~190B/thread to scratch: WRITE +100MB).
#define TILE_ELE 16384

struct G1Args { const int* idx[15]; };

__global__ __launch_bounds__(512, 2) void gemm1g(
    G1Args p, const u16* __restrict__ ebf, const u16* __restrict__ P,
    const u16* __restrict__ T, const u16* __restrict__ Wt,
    const float* __restrict__ bias, u16* __restrict__ C, int N, int gm) {
  constexpr int K = KF1;
  constexpr int NT = K / 32;   // 33
  extern __shared__ __align__(16) u16 lds[];
  uint32_t* desc32 = reinterpret_cast<uint32_t*>(&lds[49152]);    // byte 98304
  int* idxl = reinterpret_cast<int*>(&lds[49152 + 1056]);         // byte 100416
  const int tid  = threadIdx.x;
  const int w    = tid >> 6;
  const int lane = tid & 63;
  const int fr   = lane & 15;
  const int kg   = lane >> 4;
  const int wm   = w >> 2;
  const int wn   = w & 3;

  const int nwg = gridDim.x;
  const int q = nwg >> 3, r = nwg & 7;
  const int xcd = blockIdx.x & 7, lid = blockIdx.x >> 3;
  const int swz = (xcd < r) ? (xcd * (q + 1) + lid) : (r * (q + 1) + (xcd - r) * q + lid);
  const int gn = N >> 8;
  const int bn = swz % gn, bm = swz / gn;
  const int rowBase = bm * 256, colBase = bn * 256;

  // ---- preload descriptors (132 groups of 8 cols) + idx table
  if (tid < 132) {
    const int c0 = tid * 8;
    int s = 0;
#pragma unroll
    for (int t = 1; t < 8; ++t) if (c0 >= NEWOFF[t]) s = t;
    const int fid = SEGFID[s];
    const u16* base = (fid < 15) ? (ebf + EOFF[fid]) : P;
    const int dim = (fid < 15) ? FDIMd[fid] : 144;
    const int off = c0 - NEWOFF[s];
    desc32[tid * 4 + 0] = (uint32_t)(uintptr_t)base;
    desc32[tid * 4 + 1] = (uint32_t)((uintptr_t)base >> 32);
    desc32[tid * 4 + 2] = (uint32_t)dim;
    desc32[tid * 4 + 3] = (uint32_t)(off | (fid << 16));
  }
#pragma unroll
  for (int f = 0; f < 15; ++f)
    if (tid < 256) idxl[tid * 17 + f] = p.idx[f][rowBase + tid];
  if (tid < 256) idxl[tid * 17 + 15] = tid;   // pooled: P is chunk-local
  __syncthreads();

  const int srow  = lane >> 2;
  const int sslot = (lane & 3) ^ ((lane >> 3) & 3);
  const u16* Bsrc0 = Wt + (size_t)(colBase + w * 16 + srow) * K + sslot * 8;
  const size_t rstep = (size_t)128 * K;
  const int r0 = w * 16 + srow;

  f32x4 acc[8][4];
#pragma unroll
  for (int m = 0; m < 8; ++m)
#pragma unroll
    for (int n = 0; n < 4; ++n)
      acc[m][n] = f32x4{0.f, 0.f, 0.f, 0.f};

  const int aslot8 = (kg ^ ((fr >> 1) & 3)) * 8;
  const int ardA = (wm * 128 + fr) * 32 + aslot8;
  const int ardB = (wn * 64 + fr) * 32 + aslot8 + 8192;

  auto stageA = [&](int ldsElemBase, int kt) {
    const int g = kt * 4 + sslot;
    const uint32_t d0 = desc32[g * 4 + 0];
    const uint32_t d1 = desc32[g * 4 + 1];
    const uint32_t d2 = desc32[g * 4 + 2];
    const uint32_t d3 = desc32[g * 4 + 3];
    const u16* base = (const u16*)(((uint64_t)d1 << 32) | (uint64_t)d0);
    const int dim = (int)d2;
    const int off = (int)(d3 & 0xffffu);
    const int fid = (int)(d3 >> 16);
    const int i0 = idxl[r0 * 17 + fid];
    const int i1 = idxl[(r0 + 128) * 17 + fid];
    gload16(base + (size_t)i0 * dim + off, &lds[ldsElemBase + w * 512]);
    gload16(base + (size_t)i1 * dim + off, &lds[ldsElemBase + w * 512 + 4096]);
  };
  auto stageB = [&](int ldsElemBase, int kt) {
    const u16* s = Bsrc0 + (size_t)kt * 32;
    gload16(s,         &lds[ldsElemBase + w * 512]);
    gload16(s + rstep, &lds[ldsElemBase + w * 512 + 4096]);
  };

  stageA(0 * TILE_ELE,        0);
  stageB(0 * TILE_ELE + 8192, 0);
  stageA(1 * TILE_ELE,        1);
  stageB(1 * TILE_ELE + 8192, 1);

  for (int t = 0; t < NT; ++t) {
    const int cb = t % 3;
    const int sb = (t + 2) % 3;
    const bool dost = (t + 2) < NT;
    const int cA = cb * TILE_ELE;

    __builtin_amdgcn_sched_barrier(0);
    if (t < NT - 1) asm volatile("s_waitcnt vmcnt(4)" ::: "memory");
    else            asm volatile("s_waitcnt vmcnt(0)" ::: "memory");
    __builtin_amdgcn_s_barrier();
    __builtin_amdgcn_sched_barrier(0);

    if (dost) {
      stageA(sb * TILE_ELE,        t + 2);
      stageB(sb * TILE_ELE + 8192, t + 2);
    }

    bf16x8 a0 = *(const bf16x8*)&lds[cA + ardA + 0 * 512];
    bf16x8 a1 = *(const bf16x8*)&lds[cA + ardA + 1 * 512];
    bf16x8 a2 = *(const bf16x8*)&lds[cA + ardA + 2 * 512];
    bf16x8 a3 = *(const bf16x8*)&lds[cA + ardA + 3 * 512];
    bf16x8 b0 = *(const bf16x8*)&lds[cA + ardB + 0 * 512];
    bf16x8 b1 = *(const bf16x8*)&lds[cA + ardB + 1 * 512];
    bf16x8 b2 = *(const bf16x8*)&lds[cA + ardB + 2 * 512];
    bf16x8 b3 = *(const bf16x8*)&lds[cA + ardB + 3 * 512];
    bf16x8 c0 = *(const bf16x8*)&lds[cA + ardA + 2048 + 0 * 512];
    bf16x8 c1 = *(const bf16x8*)&lds[cA + ardA + 2048 + 1 * 512];
    bf16x8 c2 = *(const bf16x8*)&lds[cA + ardA + 2048 + 2 * 512];
    bf16x8 c3 = *(const bf16x8*)&lds[cA + ardA + 2048 + 3 * 512];
#pragma unroll
    for (int n = 0; n < 4; ++n) {
      bf16x8 bf = (n == 0) ? b0 : (n == 1) ? b1 : (n == 2) ? b2 : b3;
      acc[0][n] = __builtin_amdgcn_mfma_f32_16x16x32_bf16(bf, a0, acc[0][n], 0, 0, 0);
      acc[1][n] = __builtin_amdgcn_mfma_f32_16x16x32_bf16(bf, a1, acc[1][n], 0, 0, 0);
      acc[2][n] = __builtin_amdgcn_mfma_f32_16x16x32_bf16(bf, a2, acc[2][n], 0, 0, 0);
      acc[3][n] = __builtin_amdgcn_mfma_f32_16x16x32_bf16(bf, a3, acc[3][n], 0, 0, 0);
      acc[4][n] = __builtin_amdgcn_mfma_f32_16x16x32_bf16(bf, c0, acc[4][n], 0, 0, 0);
      acc[5][n] = __builtin_amdgcn_mfma_f32_16x16x32_bf16(bf, c1, acc[5][n], 0, 0, 0);
      acc[6][n] = __builtin_amdgcn_mfma_f32_16x16x32_bf16(bf, c2, acc[6][n], 0, 0, 0);
      acc[7][n] = __builtin_amdgcn_mfma_f32_16x16x32_bf16(bf, c3, acc[7][n], 0, 0, 0);
    }
  }

  // epilogue: += folded-T rows, bias, relu, packed store. unroll-1 on mm so
  // only one acc row's worth of temps is live at a time (no scratch spill).
#pragma unroll 1
  for (int mm = 0; mm < 8; ++mm) {
    const int rl  = wm * 128 + (mm >> 2) * 64 + (mm & 3) * 16 + fr;
    const int row = rowBase + rl;
    int tr[8];
#pragma unroll
    for (int g = 0; g < 8; ++g)
      tr[g] = (TROWc[g] + idxl[rl * 17 + FOLDF[g]]) << 10;   // *1024
#pragma unroll
    for (int n = 0; n < 4; ++n) {
      const int col0 = colBase + wn * 64 + n * 16 + kg * 4;
      float s0 = 0.f, s1 = 0.f, s2 = 0.f, s3 = 0.f;
#pragma unroll
      for (int g = 0; g < 8; ++g) {
        const ushort4 tv = *reinterpret_cast<const ushort4*>(&T[tr[g] + col0]);
        s0 += bf2f(tv.x); s1 += bf2f(tv.y); s2 += bf2f(tv.z); s3 += bf2f(tv.w);
      }
      ushort4 o;
      o.x = f2bf(fmaxf(acc[mm][n][0] + bias[col0 + 0] + s0, 0.f));
      o.y = f2bf(fmaxf(acc[mm][n][1] + bias[col0 + 1] + s1, 0.f));
      o.z = f2bf(fmaxf(acc[mm][n][2] + bias[col0 + 2] + s2, 0.f));
      o.w = f2bf(fmaxf(acc[mm][n][3] + bias[col0 + 3] + s3, 0.f));
      *reinterpret_cast<ushort4*>(&C[(size_t)row * N + col0]) = o;
    }
  }
}

// ---------------- gemm8: R15 version (3-buffer counted vmcnt + bn-fast swizzle)
__global__ __launch_bounds__(512, 2) void gemm8(
    const u16* __restrict__ A, const u16* __restrict__ Wt,
    const float* __restrict__ bias, u16* __restrict__ C,
    int M, int N, int K, int gm) {
  extern __shared__ __align__(16) u16 lds[];
  const int tid  = threadIdx.x;
  const int w    = tid >> 6;
  const int lane = tid & 63;
  const int fr   = lane & 15;
  const int kg   = lane >> 4;
  const int wm   = w >> 2;
  const int wn   = w & 3;

  const int nwg = gridDim.x;
  const int q = nwg >> 3, r = nwg & 7;
  const int xcd = blockIdx.x & 7, lid = blockIdx.x >> 3;
  const int swz = (xcd < r) ? (xcd * (q + 1) + lid) : (r * (q + 1) + (xcd - r) * q + lid);
  const int gn = N >> 8;
  const int bn = swz % gn, bm = swz / gn;
  const int rowBase = bm * 256, colBase = bn * 256;

  const int srow  = lane >> 2;
  const int sslot = (lane & 3) ^ ((lane >> 3) & 3);
  const u16* Asrc0 = A  + (size_t)(rowBase + w * 16 + srow) * K + sslot * 8;
  const u16* Bsrc0 = Wt + (size_t)(colBase + w * 16 + srow) * K + sslot * 8;
  const size_t rstep = (size_t)128 * K;

  const int NT = K / 32;

  f32x4 acc[8][4];
#pragma unroll
  for (int m = 0; m < 8; ++m)
#pragma unroll
    for (int n = 0; n < 4; ++n)
      acc[m][n] = f32x4{0.f, 0.f, 0.f, 0.f};

  const int aslot8 = (kg ^ ((fr >> 1) & 3)) * 8;
  const int ardA = (wm * 128 + fr) * 32 + aslot8;
  const int ardB = (wn * 64 + fr) * 32 + aslot8 + 8192;

  auto stage = [&](const u16* src0, int ldsElemBase, int kt) {
    const u16* s = src0 + (size_t)kt * 32;
    gload16(s,         &lds[ldsElemBase + w * 512]);
    gload16(s + rstep, &lds[ldsElemBase + w * 512 + 4096]);
  };

  stage(Asrc0, 0 * TILE_ELE,        0);
  stage(Bsrc0, 0 * TILE_ELE + 8192, 0);
  stage(Asrc0, 1 * TILE_ELE,        1);
  stage(Bsrc0, 1 * TILE_ELE + 8192, 1);

  for (int t = 0; t < NT; ++t) {
    const int cb = t % 3;
    const int sb = (t + 2) % 3;
    const bool dost = (t + 2) < NT;
    const int cA = cb * TILE_ELE;

    __builtin_amdgcn_sched_barrier(0);
    if (t < NT - 1) asm volatile("s_waitcnt vmcnt(4)" ::: "memory");
    else            asm volatile("s_waitcnt vmcnt(0)" ::: "memory");
    __builtin_amdgcn_s_barrier();
    __builtin_amdgcn_sched_barrier(0);

    bf16x8 a0 = *(const bf16x8*)&lds[cA + ardA + 0 * 512];
    bf16x8 a1 = *(const bf16x8*)&lds[cA + ardA + 1 * 512];
    bf16x8 a2 = *(const bf16x8*)&lds[cA + ardA + 2 * 512];
    bf16x8 a3 = *(const bf16x8*)&lds[cA + ardA + 3 * 512];
    bf16x8 b0 = *(const bf16x8*)&lds[cA + ardB + 0 * 512];
    bf16x8 b1 = *(const bf16x8*)&lds[cA + ardB + 1 * 512];
    bf16x8 b2 = *(const bf16x8*)&lds[cA + ardB + 2 * 512];
    bf16x8 b3 = *(const bf16x8*)&lds[cA + ardB + 3 * 512];
    bf16x8 c0 = *(const bf16x8*)&lds[cA + ardA + 2048 + 0 * 512];
    bf16x8 c1 = *(const bf16x8*)&lds[cA + ardA + 2048 + 1 * 512];
    bf16x8 c2 = *(const bf16x8*)&lds[cA + ardA + 2048 + 2 * 512];
    bf16x8 c3 = *(const bf16x8*)&lds[cA + ardA + 2048 + 3 * 512];
    if (dost) {
      stage(Asrc0, sb * TILE_ELE,        t + 2);
      stage(Bsrc0, sb * TILE_ELE + 8192, t + 2);
    }
#pragma unroll
    for (int n = 0; n < 4; ++n) {
      bf16x8 bf = (n == 0) ? b0 : (n == 1) ? b1 : (n == 2) ? b2 : b3;
      acc[0][n] = __builtin_amdgcn_mfma_f32_16x16x32_bf16(bf, a0, acc[0][n], 0, 0, 0);
      acc[1][n] = __builtin_amdgcn_mfma_f32_16x16x32_bf16(bf, a1, acc[1][n], 0, 0, 0);
      acc[2][n] = __builtin_amdgcn_mfma_f32_16x16x32_bf16(bf, a2, acc[2][n], 0, 0, 0);
      acc[3][n] = __builtin_amdgcn_mfma_f32_16x16x32_bf16(bf, a3, acc[3][n], 0, 0, 0);
      acc[4][n] = __builtin_amdgcn_mfma_f32_16x16x32_bf16(bf, c0, acc[4][n], 0, 0, 0);
      acc[5][n] = __builtin_amdgcn_mfma_f32_16x16x32_bf16(bf, c1, acc[5][n], 0, 0, 0);
      acc[6][n] = __builtin_amdgcn_mfma_f32_16x16x32_bf16(bf, c2, acc[6][n], 0, 0, 0);
      acc[7][n] = __builtin_amdgcn_mfma_f32_16x16x32_bf16(bf, c3, acc[7][n], 0, 0, 0);
    }
  }

#pragma unroll
  for (int mm = 0; mm < 8; ++mm) {
    const int row = rowBase + wm * 128 + (mm >> 2) * 64 + (mm & 3) * 16 + fr;
#pragma unroll
    for (int n = 0; n < 4; ++n) {
      const int col0 = colBase + wn * 64 + n * 16 + kg * 4;
      ushort4 o;
      o.x = f2bf(fmaxf(acc[mm][n][0] + bias[col0 + 0], 0.f));
      o.y = f2bf(fmaxf(acc[mm][n][1] + bias[col0 + 1], 0.f));
      o.z = f2bf(fmaxf(acc[mm][n][2] + bias[col0 + 2], 0.f));
      o.w = f2bf(fmaxf(acc[mm][n][3] + bias[col0 + 3], 0.f));
      *reinterpret_cast<ushort4*>(&C[(size_t)row * N + col0]) = o;
    }
  }
}

// ---------------- gemm3f: fused GEMM3 (128x256 tile, K=512) + W4 GEMV + softmax
__global__ __launch_bounds__(512, 2) void gemm3f(
    const u16* __restrict__ A, const u16* __restrict__ Wt,
    const float* __restrict__ bias, const float* __restrict__ W4,
    const float* __restrict__ b4, float* __restrict__ out, int gm) {
  constexpr int K = 512, NT = 16;
  __shared__ __align__(16) u16 lds[2][12288];
  __shared__ float w4s[512];
  __shared__ float zred[4][128][2];
  const int tid  = threadIdx.x;
  const int w    = tid >> 6;
  const int lane = tid & 63;
  const int fr   = lane & 15;
  const int kg   = lane >> 4;
  const int wm   = w >> 2;
  const int wn   = w & 3;

  const int nwg = gridDim.x;
  const int q = nwg >> 3, r = nwg & 7;
  const int xcd = blockIdx.x & 7, lid = blockIdx.x >> 3;
  const int swz = (xcd < r) ? (xcd * (q + 1) + lid) : (r * (q + 1) + (xcd - r) * q + lid);
  const int rowBase = swz * 128;

  if (tid < 512) w4s[tid] = W4[tid];

  const int xslot = (tid & 3) ^ ((tid >> 3) & 3);
  const u16* Asrc  = A  + (size_t)(rowBase + (tid >> 2)) * K + xslot * 8;
  const u16* Bsrc0 = Wt + (size_t)(tid >> 2) * K + xslot * 8;
  const u16* Bsrc1 = Wt + (size_t)((tid >> 2) + 128) * K + xslot * 8;

  auto stage = [&](int buf, int kt) {
    const int ko = kt * 32;
    gload16(Asrc  + ko, &lds[buf][tid * 8]);
    gload16(Bsrc0 + ko, &lds[buf][4096 + tid * 8]);
    gload16(Bsrc1 + ko, &lds[buf][8192 + tid * 8]);
  };

  f32x4 acc[4][4];
#pragma unroll
  for (int m = 0; m < 4; ++m)
#pragma unroll
    for (int n = 0; n < 4; ++n)
      acc[m][n] = f32x4{0.f, 0.f, 0.f, 0.f};

  const int aslot8 = (kg ^ ((fr >> 1) & 3)) * 8;
  const int ardA = (wm * 64 + fr) * 32 + aslot8;
  const int ardB = 4096 + (wn * 64 + fr) * 32 + aslot8;

  stage(0, 0);
  stage(1, 1);

  for (int t = 0; t < NT; ++t) {
    const int cb = t & 1;
    if (t < NT - 1) asm volatile("s_waitcnt vmcnt(3)" ::: "memory");
    else            asm volatile("s_waitcnt vmcnt(0)" ::: "memory");
    __builtin_amdgcn_s_barrier();

    bf16x8 a0 = *(const bf16x8*)&lds[cb][ardA + 0 * 512];
    bf16x8 a1 = *(const bf16x8*)&lds[cb][ardA + 1 * 512];
    bf16x8 a2 = *(const bf16x8*)&lds[cb][ardA + 2 * 512];
    bf16x8 a3 = *(const bf16x8*)&lds[cb][ardA + 3 * 512];
    bf16x8 b0 = *(const bf16x8*)&lds[cb][ardB + 0 * 512];
    bf16x8 b1 = *(const bf16x8*)&lds[cb][ardB + 1 * 512];
    bf16x8 b2 = *(const bf16x8*)&lds[cb][ardB + 2 * 512];
    bf16x8 b3 = *(const bf16x8*)&lds[cb][ardB + 3 * 512];
    asm volatile("s_waitcnt lgkmcnt(0)" ::: "memory");
    __builtin_amdgcn_s_barrier();
    if (t + 2 < NT) stage(cb, t + 2);
    __builtin_amdgcn_sched_barrier(0);
    __builtin_amdgcn_s_setprio(1);
#pragma unroll
    for (int n = 0; n < 4; ++n) {
      bf16x8 bf = (n == 0) ? b0 : (n == 1) ? b1 : (n == 2) ? b2 : b3;
      acc[0][n] = __builtin_amdgcn_mfma_f32_16x16x32_bf16(bf, a0, acc[0][n], 0, 0, 0);
      acc[1][n] = __builtin_amdgcn_mfma_f32_16x16x32_bf16(bf, a1, acc[1][n], 0, 0, 0);
      acc[2][n] = __builtin_amdgcn_mfma_f32_16x16x32_bf16(bf, a2, acc[2][n], 0, 0, 0);
      acc[3][n] = __builtin_amdgcn_mfma_f32_16x16x32_bf16(bf, a3, acc[3][n], 0, 0, 0);
    }
    __builtin_amdgcn_s_setprio(0);
  }

  float z0[4] = {0.f, 0.f, 0.f, 0.f};
  float z1[4] = {0.f, 0.f, 0.f, 0.f};
#pragma unroll
  for (int n = 0; n < 4; ++n) {
    const int col0 = wn * 64 + n * 16 + kg * 4;
#pragma unroll
    for (int j = 0; j < 4; ++j) {
      const int c = col0 + j;
      const float bv = bias[c];
      const float w40 = w4s[c * 2];
      const float w41 = w4s[c * 2 + 1];
#pragma unroll
      for (int m = 0; m < 4; ++m) {
        const float h = fmaxf(acc[m][n][j] + bv, 0.f);
        z0[m] += h * w40;
        z1[m] += h * w41;
      }
    }
  }
#pragma unroll
  for (int m = 0; m < 4; ++m) {
    z0[m] += __shfl_xor(z0[m], 16); z0[m] += __shfl_xor(z0[m], 32);
    z1[m] += __shfl_xor(z1[m], 16); z1[m] += __shfl_xor(z1[m], 32);
  }
  if (kg == 0) {
#pragma unroll
    for (int m = 0; m < 4; ++m) {
      const int rr = wm * 64 + m * 16 + fr;
      zred[wn][rr][0] = z0[m];
      zred[wn][rr][1] = z1[m];
    }
  }
  __syncthreads();
  if (tid < 128) {
    const float s0 = zred[0][tid][0] + zred[1][tid][0] + zred[2][tid][0] + zred[3][tid][0];
    const float s1 = zred[0][tid][1] + zred[1][tid][1] + zred[2][tid][1] + zred[3][tid][1];
    const float zz0 = fmaxf(s0 + b4[0], 0.f);
    const float zz1 = fmaxf(s1 + b4[1], 0.f);
    const float mx = fmaxf(zz0, zz1);
    const float e0 = __expf(zz0 - mx), e1 = __expf(zz1 - mx);
    const float inv = 1.0f / (e0 + e1);
    out[(size_t)(rowBase + tid) * 2]     = e0 * inv;
    out[(size_t)(rowBase + tid) * 2 + 1] = e1 * inv;
  }
}

// ---------------- host side
extern "C" void kernel_launch(void* const* d_in, const int* in_sizes, int n_in,
                              void* d_out, int out_size, void* d_ws, size_t ws_size,
                              hipStream_t stream) {
  const float* W1 = (const float*)d_in[32];
  const float* b1 = (const float*)d_in[33];
  const float* W2 = (const float*)d_in[34];
  const float* b2 = (const float*)d_in[35];
  const float* W3 = (const float*)d_in[36];
  const float* b3 = (const float*)d_in[37];
  const float* W4 = (const float*)d_in[38];
  const float* b4 = (const float*)d_in[39];

  (void)hipFuncSetAttribute(reinterpret_cast<const void*>(&gemm8),
                            hipFuncAttributeMaxDynamicSharedMemorySize, 98304);
  (void)hipFuncSetAttribute(reinterpret_cast<const void*>(&gemm1g),
                            hipFuncAttributeMaxDynamicSharedMemorySize, 117824);

  char* ws = (char*)d_ws;
  size_t off = 0;
  auto alloc = [&](size_t bytes) -> void* {
    void* p = ws + off;
    off += (bytes + 255) & ~(size_t)255;
    return p;
  };

  u16* W1t = (u16*)alloc((size_t)1024 * KF1 * 2);
  u16* W2t = (u16*)alloc((size_t)512 * 1024 * 2);
  u16* W3t = (u16*)alloc((size_t)256 * 512 * 2);
  u16* ebf = (u16*)alloc((size_t)EBF_TOTAL * 2);
  u16* T   = (u16*)alloc((size_t)92 * 1024 * 2);
  const size_t fixed = off;

  // per-chunk: P (Bc x 144) + H1 (Bc x 1024) + H2 (Bc x 512), bf16
  int nc = 64;
  const int cands[7] = {1, 2, 4, 8, 16, 32, 64};
  for (int ci = 0; ci < 7; ++ci) {
    size_t Bc = (size_t)B_TOTAL / cands[ci];
    size_t need = fixed + Bc * (144 + 1024 + 512) * 2 + 4096;
    if (need <= ws_size) { nc = cands[ci]; break; }
  }
  const int Bc = B_TOTAL / nc;

  u16* P  = (u16*)alloc((size_t)Bc * 144 * 2);
  u16* H1 = (u16*)alloc((size_t)Bc * 1024 * 2);
  u16* H2 = (u16*)alloc((size_t)Bc * 512 * 2);

  wprep1_kernel<<<(1024 * KF1 + 255) / 256, 256, 0, stream>>>(W1, W1t);
  wprep_kernel<<<(512 * 1024 + 255) / 256, 256, 0, stream>>>(W2, W2t, 1024, 512, 1024);
  wprep_kernel<<<(256 * 512 + 255) / 256, 256, 0, stream>>>(W3, W3t, 512, 256, 512);

  EcvtArgs ea;
  for (int f = 0; f < 15; ++f) ea.E[f] = (const float*)d_in[2 * f + 1];
  ecvt_kernel<<<(EBF_TOTAL + 255) / 256, 256, 0, stream>>>(ea, ebf);

  TprepArgs ta;
  {
    const int foldf[8] = {3, 4, 5, 7, 8, 9, 10, 13};
    for (int g = 0; g < 8; ++g) ta.E[g] = (const float*)d_in[2 * foldf[g] + 1];
  }
  tprep_kernel<<<(92 * 1024 + 255) / 256, 256, 0, stream>>>(ta, W1, T);

  G1Args g1;
  for (int f = 0; f < 15; ++f) g1.idx[f] = (const int*)d_in[2 * f];
  const int* idx_u = (const int*)d_in[30];
  const float* E_u = (const float*)d_in[31];

  const int gm = Bc / 256;
  for (int c = 0; c < nc; ++c) {
    G1Args g1c = g1;
    for (int f = 0; f < 15; ++f) g1c.idx[f] = g1.idx[f] + c * Bc;
    pool_kernel<<<Bc / 16, 512, 0, stream>>>(idx_u, E_u, P, c * Bc);
    gemm1g<<<gm * (1024 / 256), 512, 117824, stream>>>(g1c, ebf, P, T, W1t, b1, H1, 1024, gm);
    gemm8<<<gm * (512 / 256), 512, 98304, stream>>>(H1, W2t, b2, H2, Bc, 512, 1024, gm);
    gemm3f<<<Bc / 128, 512, 0, stream>>>(H2, W3t, b3, W4, b4,
                                         (float*)d_out + (size_t)c * Bc * 2, Bc / 128);
  }
}

// Round 23
// 504.362 us; speedup vs baseline: 1.2186x; 1.2186x over previous
//
#include <hip/hip_runtime.h>
#include <stdint.h>

typedef unsigned short u16;
typedef __attribute__((ext_vector_type(8))) __bf16 bf16x8;
typedef __attribute__((ext_vector_type(4))) float f32x4;

#define B_TOTAL 65536
#define KF1     1056   // GEMM1 K after folding 8 small-vocab features (was 1440)

__device__ __forceinline__ u16 f2bf(float f) {
  union { float f; uint32_t u; } v; v.f = f;
  uint32_t r = v.u + 0x7fffu + ((v.u >> 16) & 1u);
  return (u16)(r >> 16);
}
__device__ __forceinline__ float bf2f(u16 h) {
  union { uint32_t u; float f; } v; v.u = ((uint32_t)h) << 16;
  return v.f;
}

__device__ __forceinline__ void gload16(const void* g, void* lds) {
  __builtin_amdgcn_global_load_lds(
      (const __attribute__((address_space(1))) uint32_t*)g,
      (__attribute__((address_space(3))) uint32_t*)lds, 16, 0, 0);
}

// Remaining K layout (7 singles + pool): seg bases in new K
__device__ __constant__ int NEWOFF[9] = {0,128,256,384,528,672,768,912,1056};
__device__ __constant__ int SEGFID[8] = {0,1,2,6,11,12,14,15};     // feature id per seg
__device__ __constant__ int SOLDX[8]  = {0,128,256,512,912,1056,1168,1312}; // orig X col base
// ebf blob offsets (all 15 tables; only remaining singles used by desc)
__device__ __constant__ int EOFF[15] = {0,32768,65536,98304,98336,98368,101728,
                                        155008,155584,157264,158160,158496,
                                        198096,203568,203600};
__device__ __constant__ int FDIMd[15] = {128,128,128,16,16,96,144,64,80,64,48,144,96,16,144};
#define EBF_TOTAL 246080
// Folded features: T[92][1024] = E_g . W1_g
__device__ __constant__ int TROWc[8] = {0,2,4,39,48,69,83,90};     // row base per folded g
__device__ __constant__ int TDIMc[8] = {16,16,96,64,80,64,48,16};
__device__ __constant__ int TOLDX[8] = {384,400,416,656,720,800,864,1152};
__device__ __constant__ int FOLDF[8] = {3,4,5,7,8,9,10,13};        // idx-array position

// ---------------- generic weight prep: f32 [K][N] -> bf16 [N][Kpad] (for W2/W3)
__global__ void wprep_kernel(const float* __restrict__ W, u16* __restrict__ Wt,
                             int K, int N, int Kpad) {
  int o = blockIdx.x * 256 + threadIdx.x;
  if (o >= N * Kpad) return;
  int k = o % Kpad;
  int n = o / Kpad;
  float v = (k < K) ? W[(size_t)k * N + n] : 0.0f;
  Wt[o] = f2bf(v);
}

// ---------------- W1 prep with K remap: f32 W1[1424][1024] -> bf16 Wt[1024][1056]
__global__ void wprep1_kernel(const float* __restrict__ W1, u16* __restrict__ Wt) {
  int o = blockIdx.x * 256 + threadIdx.x;
  if (o >= 1024 * KF1) return;
  int k = o % KF1;
  int n = o / KF1;
  int s = 0;
#pragma unroll
  for (int t = 1; t < 8; ++t) if (k >= NEWOFF[t]) s = t;
  const int loc = k - NEWOFF[s];
  float v = 0.0f;
  if (s < 7 || loc < 112) v = W1[(size_t)(SOLDX[s] + loc) * 1024 + n];
  Wt[o] = f2bf(v);
}

// ---------------- embedding table convert: 15 f32 tables -> one bf16 blob
struct EcvtArgs { const float* E[15]; };
__global__ void ecvt_kernel(EcvtArgs p, u16* __restrict__ ebf) {
  int i = blockIdx.x * 256 + threadIdx.x;
  if (i >= EBF_TOTAL) return;
  int f = 0;
#pragma unroll
  for (int t = 1; t < 15; ++t) if (i >= EOFF[t]) f = t;
  ebf[i] = f2bf(p.E[f][i - EOFF[f]]);
}

// ---------------- tprep: T[92][1024] bf16; T[TROW[g]+v][n] = sum_d E_g[v][d]*W1[TOLDX[g]+d][n]
struct TprepArgs { const float* E[8]; };
__global__ void tprep_kernel(TprepArgs p, const float* __restrict__ W1,
                             u16* __restrict__ T) {
  int o = blockIdx.x * 256 + threadIdx.x;
  if (o >= 92 * 1024) return;
  const int n = o & 1023, rr = o >> 10;
  int g = 0;
#pragma unroll
  for (int t = 1; t < 8; ++t) if (rr >= TROWc[t]) g = t;
  const int v = rr - TROWc[g];
  const int dim = TDIMc[g];
  const float* e = p.E[g] + (size_t)v * dim;
  const float* w = W1 + (size_t)TOLDX[g] * 1024 + n;
  float s = 0.f;
  for (int d = 0; d < dim; ++d) s += e[d] * w[(size_t)d * 1024];
  T[o] = f2bf(s);
}

// ---------------- pool: userids mean over 50 -> P[Bc][144] bf16 (cols 112..143 = 0)
__global__ __launch_bounds__(512) void pool_kernel(const int* __restrict__ idx_u,
                                                   const float* __restrict__ E_u,
                                                   u16* __restrict__ P, int row_base) {
  __shared__ float eu_t[69 * 112];
  const int tid = threadIdx.x;
  {
    const float4* s4 = reinterpret_cast<const float4*>(E_u);
    float4* d4 = reinterpret_cast<float4*>(eu_t);
    for (int i = tid; i < 69 * 28; i += 512) d4[i] = s4[i];
  }
  const int lane = tid & 63;
  const int wv   = tid >> 6;
  const int row0 = blockIdx.x * 16 + wv * 2;

  const int* iu0 = idx_u + (size_t)(row_base + row0) * 50;
  const int myid0 = (lane < 50) ? iu0[lane] : 0;
  const int myid1 = (lane < 50) ? iu0[50 + lane] : 0;
  __syncthreads();

  const int half = lane >> 5;
  const int c    = lane & 31;

  auto POOL = [&](int myid, u16* prow) {
    if (c < 28) {
      float4 s = {0.f, 0.f, 0.f, 0.f};
      const float* eu = eu_t + c * 4;
      const int j0 = half * 25;
#pragma unroll
      for (int jb = 0; jb < 25; jb += 5) {
        float4 v0, v1, v2, v3, v4;
        {
          const int i0 = __shfl(myid, j0 + jb + 0);
          const int i1 = __shfl(myid, j0 + jb + 1);
          const int i2 = __shfl(myid, j0 + jb + 2);
          const int i3 = __shfl(myid, j0 + jb + 3);
          const int i4 = __shfl(myid, j0 + jb + 4);
          v0 = *reinterpret_cast<const float4*>(eu + i0 * 112);
          v1 = *reinterpret_cast<const float4*>(eu + i1 * 112);
          v2 = *reinterpret_cast<const float4*>(eu + i2 * 112);
          v3 = *reinterpret_cast<const float4*>(eu + i3 * 112);
          v4 = *reinterpret_cast<const float4*>(eu + i4 * 112);
        }
        s.x += v0.x + v1.x + v2.x + v3.x + v4.x;
        s.y += v0.y + v1.y + v2.y + v3.y + v4.y;
        s.z += v0.z + v1.z + v2.z + v3.z + v4.z;
        s.w += v0.w + v1.w + v2.w + v3.w + v4.w;
      }
      s.x += __shfl_xor(s.x, 32);
      s.y += __shfl_xor(s.y, 32);
      s.z += __shfl_xor(s.z, 32);
      s.w += __shfl_xor(s.w, 32);
      if (half == 0) {
        const float inv = 1.0f / 50.0f;
        ushort4 o;
        o.x = f2bf(s.x * inv);
        o.y = f2bf(s.y * inv);
        o.z = f2bf(s.z * inv);
        o.w = f2bf(s.w * inv);
        *reinterpret_cast<ushort4*>(prow + c * 4) = o;
      }
    } else {
      ushort4 z; z.x = 0; z.y = 0; z.z = 0; z.w = 0;
      *reinterpret_cast<ushort4*>(prow + 112 + half * 16 + (c - 28) * 4) = z;
    }
  };

  POOL(myid0, P + (size_t)row0 * 144);
  POOL(myid1, P + (size_t)(row0 + 1) * 144);
}

// ---------------- gemm1g: GEMM1 (K=1056) gather-on-stage A + folded-T epilogue
// Epilogue: FULL unroll on mm (static acc indexing, rule-20) with
// sched_barrier(0) after each (mm,n) store so at most 8 T-gathers are in
// flight (R19's spill = scheduler hoisting all 256 loads; R20's worse spill =
// runtime mm index sending acc to scratch).
#define TILE_ELE 16384

struct G1Args { const int* idx[15]; };

__global__ __launch_bounds__(512, 2) void gemm1g(
    G1Args p, const u16* __restrict__ ebf, const u16* __restrict__ P,
    const u16* __restrict__ T, const u16* __restrict__ Wt,
    const float* __restrict__ bias, u16* __restrict__ C, int N, int gm) {
  constexpr int K = KF1;
  constexpr int NT = K / 32;   // 33
  extern __shared__ __align__(16) u16 lds[];
  uint32_t* desc32 = reinterpret_cast<uint32_t*>(&lds[49152]);    // byte 98304
  int* idxl = reinterpret_cast<int*>(&lds[49152 + 1056]);         // byte 100416
  const int tid  = threadIdx.x;
  const int w    = tid >> 6;
  const int lane = tid & 63;
  const int fr   = lane & 15;
  const int kg   = lane >> 4;
  const int wm   = w >> 2;
  const int wn   = w & 3;

  const int nwg = gridDim.x;
  const int q = nwg >> 3, r = nwg & 7;
  const int xcd = blockIdx.x & 7, lid = blockIdx.x >> 3;
  const int swz = (xcd < r) ? (xcd * (q + 1) + lid) : (r * (q + 1) + (xcd - r) * q + lid);
  const int gn = N >> 8;
  const int bn = swz % gn, bm = swz / gn;
  const int rowBase = bm * 256, colBase = bn * 256;

  // ---- preload descriptors (132 groups of 8 cols) + idx table
  if (tid < 132) {
    const int c0 = tid * 8;
    int s = 0;
#pragma unroll
    for (int t = 1; t < 8; ++t) if (c0 >= NEWOFF[t]) s = t;
    const int fid = SEGFID[s];
    const u16* base = (fid < 15) ? (ebf + EOFF[fid]) : P;
    const int dim = (fid < 15) ? FDIMd[fid] : 144;
    const int off = c0 - NEWOFF[s];
    desc32[tid * 4 + 0] = (uint32_t)(uintptr_t)base;
    desc32[tid * 4 + 1] = (uint32_t)((uintptr_t)base >> 32);
    desc32[tid * 4 + 2] = (uint32_t)dim;
    desc32[tid * 4 + 3] = (uint32_t)(off | (fid << 16));
  }
#pragma unroll
  for (int f = 0; f < 15; ++f)
    if (tid < 256) idxl[tid * 17 + f] = p.idx[f][rowBase + tid];
  if (tid < 256) idxl[tid * 17 + 15] = tid;   // pooled: P is chunk-local
  __syncthreads();

  const int srow  = lane >> 2;
  const int sslot = (lane & 3) ^ ((lane >> 3) & 3);
  const u16* Bsrc0 = Wt + (size_t)(colBase + w * 16 + srow) * K + sslot * 8;
  const size_t rstep = (size_t)128 * K;
  const int r0 = w * 16 + srow;

  f32x4 acc[8][4];
#pragma unroll
  for (int m = 0; m < 8; ++m)
#pragma unroll
    for (int n = 0; n < 4; ++n)
      acc[m][n] = f32x4{0.f, 0.f, 0.f, 0.f};

  const int aslot8 = (kg ^ ((fr >> 1) & 3)) * 8;
  const int ardA = (wm * 128 + fr) * 32 + aslot8;
  const int ardB = (wn * 64 + fr) * 32 + aslot8 + 8192;

  auto stageA = [&](int ldsElemBase, int kt) {
    const int g = kt * 4 + sslot;
    const uint32_t d0 = desc32[g * 4 + 0];
    const uint32_t d1 = desc32[g * 4 + 1];
    const uint32_t d2 = desc32[g * 4 + 2];
    const uint32_t d3 = desc32[g * 4 + 3];
    const u16* base = (const u16*)(((uint64_t)d1 << 32) | (uint64_t)d0);
    const int dim = (int)d2;
    const int off = (int)(d3 & 0xffffu);
    const int fid = (int)(d3 >> 16);
    const int i0 = idxl[r0 * 17 + fid];
    const int i1 = idxl[(r0 + 128) * 17 + fid];
    gload16(base + (size_t)i0 * dim + off, &lds[ldsElemBase + w * 512]);
    gload16(base + (size_t)i1 * dim + off, &lds[ldsElemBase + w * 512 + 4096]);
  };
  auto stageB = [&](int ldsElemBase, int kt) {
    const u16* s = Bsrc0 + (size_t)kt * 32;
    gload16(s,         &lds[ldsElemBase + w * 512]);
    gload16(s + rstep, &lds[ldsElemBase + w * 512 + 4096]);
  };

  stageA(0 * TILE_ELE,        0);
  stageB(0 * TILE_ELE + 8192, 0);
  stageA(1 * TILE_ELE,        1);
  stageB(1 * TILE_ELE + 8192, 1);

  for (int t = 0; t < NT; ++t) {
    const int cb = t % 3;
    const int sb = (t + 2) % 3;
    const bool dost = (t + 2) < NT;
    const int cA = cb * TILE_ELE;

    __builtin_amdgcn_sched_barrier(0);
    if (t < NT - 1) asm volatile("s_waitcnt vmcnt(4)" ::: "memory");
    else            asm volatile("s_waitcnt vmcnt(0)" ::: "memory");
    __builtin_amdgcn_s_barrier();
    __builtin_amdgcn_sched_barrier(0);

    if (dost) {
      stageA(sb * TILE_ELE,        t + 2);
      stageB(sb * TILE_ELE + 8192, t + 2);
    }

    bf16x8 a0 = *(const bf16x8*)&lds[cA + ardA + 0 * 512];
    bf16x8 a1 = *(const bf16x8*)&lds[cA + ardA + 1 * 512];
    bf16x8 a2 = *(const bf16x8*)&lds[cA + ardA + 2 * 512];
    bf16x8 a3 = *(const bf16x8*)&lds[cA + ardA + 3 * 512];
    bf16x8 b0 = *(const bf16x8*)&lds[cA + ardB + 0 * 512];
    bf16x8 b1 = *(const bf16x8*)&lds[cA + ardB + 1 * 512];
    bf16x8 b2 = *(const bf16x8*)&lds[cA + ardB + 2 * 512];
    bf16x8 b3 = *(const bf16x8*)&lds[cA + ardB + 3 * 512];
    bf16x8 c0 = *(const bf16x8*)&lds[cA + ardA + 2048 + 0 * 512];
    bf16x8 c1 = *(const bf16x8*)&lds[cA + ardA + 2048 + 1 * 512];
    bf16x8 c2 = *(const bf16x8*)&lds[cA + ardA + 2048 + 2 * 512];
    bf16x8 c3 = *(const bf16x8*)&lds[cA + ardA + 2048 + 3 * 512];
#pragma unroll
    for (int n = 0; n < 4; ++n) {
      bf16x8 bf = (n == 0) ? b0 : (n == 1) ? b1 : (n == 2) ? b2 : b3;
      acc[0][n] = __builtin_amdgcn_mfma_f32_16x16x32_bf16(bf, a0, acc[0][n], 0, 0, 0);
      acc[1][n] = __builtin_amdgcn_mfma_f32_16x16x32_bf16(bf, a1, acc[1][n], 0, 0, 0);
      acc[2][n] = __builtin_amdgcn_mfma_f32_16x16x32_bf16(bf, a2, acc[2][n], 0, 0, 0);
      acc[3][n] = __builtin_amdgcn_mfma_f32_16x16x32_bf16(bf, a3, acc[3][n], 0, 0, 0);
      acc[4][n] = __builtin_amdgcn_mfma_f32_16x16x32_bf16(bf, c0, acc[4][n], 0, 0, 0);
      acc[5][n] = __builtin_amdgcn_mfma_f32_16x16x32_bf16(bf, c1, acc[5][n], 0, 0, 0);
      acc[6][n] = __builtin_amdgcn_mfma_f32_16x16x32_bf16(bf, c2, acc[6][n], 0, 0, 0);
      acc[7][n] = __builtin_amdgcn_mfma_f32_16x16x32_bf16(bf, c3, acc[7][n], 0, 0, 0);
    }
  }

  // epilogue: += folded-T rows, bias, relu, packed store.
  // Full unroll (static acc index); sched_barrier(0) after each group's store
  // caps in-flight T-gathers at 8 -> no register-pressure spill.
#pragma unroll
  for (int mm = 0; mm < 8; ++mm) {
    const int rl  = wm * 128 + (mm >> 2) * 64 + (mm & 3) * 16 + fr;
    const int row = rowBase + rl;
    int tr[8];
#pragma unroll
    for (int g = 0; g < 8; ++g)
      tr[g] = (TROWc[g] + idxl[rl * 17 + FOLDF[g]]) << 10;   // *1024
#pragma unroll
    for (int n = 0; n < 4; ++n) {
      const int col0 = colBase + wn * 64 + n * 16 + kg * 4;
      float s0 = 0.f, s1 = 0.f, s2 = 0.f, s3 = 0.f;
#pragma unroll
      for (int g = 0; g < 8; ++g) {
        const ushort4 tv = *reinterpret_cast<const ushort4*>(&T[tr[g] + col0]);
        s0 += bf2f(tv.x); s1 += bf2f(tv.y); s2 += bf2f(tv.z); s3 += bf2f(tv.w);
      }
      ushort4 o;
      o.x = f2bf(fmaxf(acc[mm][n][0] + bias[col0 + 0] + s0, 0.f));
      o.y = f2bf(fmaxf(acc[mm][n][1] + bias[col0 + 1] + s1, 0.f));
      o.z = f2bf(fmaxf(acc[mm][n][2] + bias[col0 + 2] + s2, 0.f));
      o.w = f2bf(fmaxf(acc[mm][n][3] + bias[col0 + 3] + s3, 0.f));
      *reinterpret_cast<ushort4*>(&C[(size_t)row * N + col0]) = o;
      __builtin_amdgcn_sched_barrier(0);
    }
  }
}

// ---------------- gemm8: R15 version (3-buffer counted vmcnt + bn-fast swizzle)
__global__ __launch_bounds__(512, 2) void gemm8(
    const u16* __restrict__ A, const u16* __restrict__ Wt,
    const float* __restrict__ bias, u16* __restrict__ C,
    int M, int N, int K, int gm) {
  extern __shared__ __align__(16) u16 lds[];
  const int tid  = threadIdx.x;
  const int w    = tid >> 6;
  const int lane = tid & 63;
  const int fr   = lane & 15;
  const int kg   = lane >> 4;
  const int wm   = w >> 2;
  const int wn   = w & 3;

  const int nwg = gridDim.x;
  const int q = nwg >> 3, r = nwg & 7;
  const int xcd = blockIdx.x & 7, lid = blockIdx.x >> 3;
  const int swz = (xcd < r) ? (xcd * (q + 1) + lid) : (r * (q + 1) + (xcd - r) * q + lid);
  const int gn = N >> 8;
  const int bn = swz % gn, bm = swz / gn;
  const int rowBase = bm * 256, colBase = bn * 256;

  const int srow  = lane >> 2;
  const int sslot = (lane & 3) ^ ((lane >> 3) & 3);
  const u16* Asrc0 = A  + (size_t)(rowBase + w * 16 + srow) * K + sslot * 8;
  const u16* Bsrc0 = Wt + (size_t)(colBase + w * 16 + srow) * K + sslot * 8;
  const size_t rstep = (size_t)128 * K;

  const int NT = K / 32;

  f32x4 acc[8][4];
#pragma unroll
  for (int m = 0; m < 8; ++m)
#pragma unroll
    for (int n = 0; n < 4; ++n)
      acc[m][n] = f32x4{0.f, 0.f, 0.f, 0.f};

  const int aslot8 = (kg ^ ((fr >> 1) & 3)) * 8;
  const int ardA = (wm * 128 + fr) * 32 + aslot8;
  const int ardB = (wn * 64 + fr) * 32 + aslot8 + 8192;

  auto stage = [&](const u16* src0, int ldsElemBase, int kt) {
    const u16* s = src0 + (size_t)kt * 32;
    gload16(s,         &lds[ldsElemBase + w * 512]);
    gload16(s + rstep, &lds[ldsElemBase + w * 512 + 4096]);
  };

  stage(Asrc0, 0 * TILE_ELE,        0);
  stage(Bsrc0, 0 * TILE_ELE + 8192, 0);
  stage(Asrc0, 1 * TILE_ELE,        1);
  stage(Bsrc0, 1 * TILE_ELE + 8192, 1);

  for (int t = 0; t < NT; ++t) {
    const int cb = t % 3;
    const int sb = (t + 2) % 3;
    const bool dost = (t + 2) < NT;
    const int cA = cb * TILE_ELE;

    __builtin_amdgcn_sched_barrier(0);
    if (t < NT - 1) asm volatile("s_waitcnt vmcnt(4)" ::: "memory");
    else            asm volatile("s_waitcnt vmcnt(0)" ::: "memory");
    __builtin_amdgcn_s_barrier();
    __builtin_amdgcn_sched_barrier(0);

    bf16x8 a0 = *(const bf16x8*)&lds[cA + ardA + 0 * 512];
    bf16x8 a1 = *(const bf16x8*)&lds[cA + ardA + 1 * 512];
    bf16x8 a2 = *(const bf16x8*)&lds[cA + ardA + 2 * 512];
    bf16x8 a3 = *(const bf16x8*)&lds[cA + ardA + 3 * 512];
    bf16x8 b0 = *(const bf16x8*)&lds[cA + ardB + 0 * 512];
    bf16x8 b1 = *(const bf16x8*)&lds[cA + ardB + 1 * 512];
    bf16x8 b2 = *(const bf16x8*)&lds[cA + ardB + 2 * 512];
    bf16x8 b3 = *(const bf16x8*)&lds[cA + ardB + 3 * 512];
    bf16x8 c0 = *(const bf16x8*)&lds[cA + ardA + 2048 + 0 * 512];
    bf16x8 c1 = *(const bf16x8*)&lds[cA + ardA + 2048 + 1 * 512];
    bf16x8 c2 = *(const bf16x8*)&lds[cA + ardA + 2048 + 2 * 512];
    bf16x8 c3 = *(const bf16x8*)&lds[cA + ardA + 2048 + 3 * 512];
    if (dost) {
      stage(Asrc0, sb * TILE_ELE,        t + 2);
      stage(Bsrc0, sb * TILE_ELE + 8192, t + 2);
    }
#pragma unroll
    for (int n = 0; n < 4; ++n) {
      bf16x8 bf = (n == 0) ? b0 : (n == 1) ? b1 : (n == 2) ? b2 : b3;
      acc[0][n] = __builtin_amdgcn_mfma_f32_16x16x32_bf16(bf, a0, acc[0][n], 0, 0, 0);
      acc[1][n] = __builtin_amdgcn_mfma_f32_16x16x32_bf16(bf, a1, acc[1][n], 0, 0, 0);
      acc[2][n] = __builtin_amdgcn_mfma_f32_16x16x32_bf16(bf, a2, acc[2][n], 0, 0, 0);
      acc[3][n] = __builtin_amdgcn_mfma_f32_16x16x32_bf16(bf, a3, acc[3][n], 0, 0, 0);
      acc[4][n] = __builtin_amdgcn_mfma_f32_16x16x32_bf16(bf, c0, acc[4][n], 0, 0, 0);
      acc[5][n] = __builtin_amdgcn_mfma_f32_16x16x32_bf16(bf, c1, acc[5][n], 0, 0, 0);
      acc[6][n] = __builtin_amdgcn_mfma_f32_16x16x32_bf16(bf, c2, acc[6][n], 0, 0, 0);
      acc[7][n] = __builtin_amdgcn_mfma_f32_16x16x32_bf16(bf, c3, acc[7][n], 0, 0, 0);
    }
  }

#pragma unroll
  for (int mm = 0; mm < 8; ++mm) {
    const int row = rowBase + wm * 128 + (mm >> 2) * 64 + (mm & 3) * 16 + fr;
#pragma unroll
    for (int n = 0; n < 4; ++n) {
      const int col0 = colBase + wn * 64 + n * 16 + kg * 4;
      ushort4 o;
      o.x = f2bf(fmaxf(acc[mm][n][0] + bias[col0 + 0], 0.f));
      o.y = f2bf(fmaxf(acc[mm][n][1] + bias[col0 + 1], 0.f));
      o.z = f2bf(fmaxf(acc[mm][n][2] + bias[col0 + 2], 0.f));
      o.w = f2bf(fmaxf(acc[mm][n][3] + bias[col0 + 3], 0.f));
      *reinterpret_cast<ushort4*>(&C[(size_t)row * N + col0]) = o;
    }
  }
}

// ---------------- gemm3f: fused GEMM3 (128x256 tile, K=512) + W4 GEMV + softmax
__global__ __launch_bounds__(512, 2) void gemm3f(
    const u16* __restrict__ A, const u16* __restrict__ Wt,
    const float* __restrict__ bias, const float* __restrict__ W4,
    const float* __restrict__ b4, float* __restrict__ out, int gm) {
  constexpr int K = 512, NT = 16;
  __shared__ __align__(16) u16 lds[2][12288];
  __shared__ float w4s[512];
  __shared__ float zred[4][128][2];
  const int tid  = threadIdx.x;
  const int w    = tid >> 6;
  const int lane = tid & 63;
  const int fr   = lane & 15;
  const int kg   = lane >> 4;
  const int wm   = w >> 2;
  const int wn   = w & 3;

  const int nwg = gridDim.x;
  const int q = nwg >> 3, r = nwg & 7;
  const int xcd = blockIdx.x & 7, lid = blockIdx.x >> 3;
  const int swz = (xcd < r) ? (xcd * (q + 1) + lid) : (r * (q + 1) + (xcd - r) * q + lid);
  const int rowBase = swz * 128;

  if (tid < 512) w4s[tid] = W4[tid];

  const int xslot = (tid & 3) ^ ((tid >> 3) & 3);
  const u16* Asrc  = A  + (size_t)(rowBase + (tid >> 2)) * K + xslot * 8;
  const u16* Bsrc0 = Wt + (size_t)(tid >> 2) * K + xslot * 8;
  const u16* Bsrc1 = Wt + (size_t)((tid >> 2) + 128) * K + xslot * 8;

  auto stage = [&](int buf, int kt) {
    const int ko = kt * 32;
    gload16(Asrc  + ko, &lds[buf][tid * 8]);
    gload16(Bsrc0 + ko, &lds[buf][4096 + tid * 8]);
    gload16(Bsrc1 + ko, &lds[buf][8192 + tid * 8]);
  };

  f32x4 acc[4][4];
#pragma unroll
  for (int m = 0; m < 4; ++m)
#pragma unroll
    for (int n = 0; n < 4; ++n)
      acc[m][n] = f32x4{0.f, 0.f, 0.f, 0.f};

  const int aslot8 = (kg ^ ((fr >> 1) & 3)) * 8;
  const int ardA = (wm * 64 + fr) * 32 + aslot8;
  const int ardB = 4096 + (wn * 64 + fr) * 32 + aslot8;

  stage(0, 0);
  stage(1, 1);

  for (int t = 0; t < NT; ++t) {
    const int cb = t & 1;
    if (t < NT - 1) asm volatile("s_waitcnt vmcnt(3)" ::: "memory");
    else            asm volatile("s_waitcnt vmcnt(0)" ::: "memory");
    __builtin_amdgcn_s_barrier();

    bf16x8 a0 = *(const bf16x8*)&lds[cb][ardA + 0 * 512];
    bf16x8 a1 = *(const bf16x8*)&lds[cb][ardA + 1 * 512];
    bf16x8 a2 = *(const bf16x8*)&lds[cb][ardA + 2 * 512];
    bf16x8 a3 = *(const bf16x8*)&lds[cb][ardA + 3 * 512];
    bf16x8 b0 = *(const bf16x8*)&lds[cb][ardB + 0 * 512];
    bf16x8 b1 = *(const bf16x8*)&lds[cb][ardB + 1 * 512];
    bf16x8 b2 = *(const bf16x8*)&lds[cb][ardB + 2 * 512];
    bf16x8 b3 = *(const bf16x8*)&lds[cb][ardB + 3 * 512];
    asm volatile("s_waitcnt lgkmcnt(0)" ::: "memory");
    __builtin_amdgcn_s_barrier();
    if (t + 2 < NT) stage(cb, t + 2);
    __builtin_amdgcn_sched_barrier(0);
    __builtin_amdgcn_s_setprio(1);
#pragma unroll
    for (int n = 0; n < 4; ++n) {
      bf16x8 bf = (n == 0) ? b0 : (n == 1) ? b1 : (n == 2) ? b2 : b3;
      acc[0][n] = __builtin_amdgcn_mfma_f32_16x16x32_bf16(bf, a0, acc[0][n], 0, 0, 0);
      acc[1][n] = __builtin_amdgcn_mfma_f32_16x16x32_bf16(bf, a1, acc[1][n], 0, 0, 0);
      acc[2][n] = __builtin_amdgcn_mfma_f32_16x16x32_bf16(bf, a2, acc[2][n], 0, 0, 0);
      acc[3][n] = __builtin_amdgcn_mfma_f32_16x16x32_bf16(bf, a3, acc[3][n], 0, 0, 0);
    }
    __builtin_amdgcn_s_setprio(0);
  }

  float z0[4] = {0.f, 0.f, 0.f, 0.f};
  float z1[4] = {0.f, 0.f, 0.f, 0.f};
#pragma unroll
  for (int n = 0; n < 4; ++n) {
    const int col0 = wn * 64 + n * 16 + kg * 4;
#pragma unroll
    for (int j = 0; j < 4; ++j) {
      const int c = col0 + j;
      const float bv = bias[c];
      const float w40 = w4s[c * 2];
      const float w41 = w4s[c * 2 + 1];
#pragma unroll
      for (int m = 0; m < 4; ++m) {
        const float h = fmaxf(acc[m][n][j] + bv, 0.f);
        z0[m] += h * w40;
        z1[m] += h * w41;
      }
    }
  }
#pragma unroll
  for (int m = 0; m < 4; ++m) {
    z0[m] += __shfl_xor(z0[m], 16); z0[m] += __shfl_xor(z0[m], 32);
    z1[m] += __shfl_xor(z1[m], 16); z1[m] += __shfl_xor(z1[m], 32);
  }
  if (kg == 0) {
#pragma unroll
    for (int m = 0; m < 4; ++m) {
      const int rr = wm * 64 + m * 16 + fr;
      zred[wn][rr][0] = z0[m];
      zred[wn][rr][1] = z1[m];
    }
  }
  __syncthreads();
  if (tid < 128) {
    const float s0 = zred[0][tid][0] + zred[1][tid][0] + zred[2][tid][0] + zred[3][tid][0];
    const float s1 = zred[0][tid][1] + zred[1][tid][1] + zred[2][tid][1] + zred[3][tid][1];
    const float zz0 = fmaxf(s0 + b4[0], 0.f);
    const float zz1 = fmaxf(s1 + b4[1], 0.f);
    const float mx = fmaxf(zz0, zz1);
    const float e0 = __expf(zz0 - mx), e1 = __expf(zz1 - mx);
    const float inv = 1.0f / (e0 + e1);
    out[(size_t)(rowBase + tid) * 2]     = e0 * inv;
    out[(size_t)(rowBase + tid) * 2 + 1] = e1 * inv;
  }
}

// ---------------- host side
extern "C" void kernel_launch(void* const* d_in, const int* in_sizes, int n_in,
                              void* d_out, int out_size, void* d_ws, size_t ws_size,
                              hipStream_t stream) {
  const float* W1 = (const float*)d_in[32];
  const float* b1 = (const float*)d_in[33];
  const float* W2 = (const float*)d_in[34];
  const float* b2 = (const float*)d_in[35];
  const float* W3 = (const float*)d_in[36];
  const float* b3 = (const float*)d_in[37];
  const float* W4 = (const float*)d_in[38];
  const float* b4 = (const float*)d_in[39];

  (void)hipFuncSetAttribute(reinterpret_cast<const void*>(&gemm8),
                            hipFuncAttributeMaxDynamicSharedMemorySize, 98304);
  (void)hipFuncSetAttribute(reinterpret_cast<const void*>(&gemm1g),
                            hipFuncAttributeMaxDynamicSharedMemorySize, 117824);

  char* ws = (char*)d_ws;
  size_t off = 0;
  auto alloc = [&](size_t bytes) -> void* {
    void* p = ws + off;
    off += (bytes + 255) & ~(size_t)255;
    return p;
  };

  u16* W1t = (u16*)alloc((size_t)1024 * KF1 * 2);
  u16* W2t = (u16*)alloc((size_t)512 * 1024 * 2);
  u16* W3t = (u16*)alloc((size_t)256 * 512 * 2);
  u16* ebf = (u16*)alloc((size_t)EBF_TOTAL * 2);
  u16* T   = (u16*)alloc((size_t)92 * 1024 * 2);
  const size_t fixed = off;

  // per-chunk: P (Bc x 144) + H1 (Bc x 1024) + H2 (Bc x 512), bf16
  int nc = 64;
  const int cands[7] = {1, 2, 4, 8, 16, 32, 64};
  for (int ci = 0; ci < 7; ++ci) {
    size_t Bc = (size_t)B_TOTAL / cands[ci];
    size_t need = fixed + Bc * (144 + 1024 + 512) * 2 + 4096;
    if (need <= ws_size) { nc = cands[ci]; break; }
  }
  const int Bc = B_TOTAL / nc;

  u16* P  = (u16*)alloc((size_t)Bc * 144 * 2);
  u16* H1 = (u16*)alloc((size_t)Bc * 1024 * 2);
  u16* H2 = (u16*)alloc((size_t)Bc * 512 * 2);

  wprep1_kernel<<<(1024 * KF1 + 255) / 256, 256, 0, stream>>>(W1, W1t);
  wprep_kernel<<<(512 * 1024 + 255) / 256, 256, 0, stream>>>(W2, W2t, 1024, 512, 1024);
  wprep_kernel<<<(256 * 512 + 255) / 256, 256, 0, stream>>>(W3, W3t, 512, 256, 512);

  EcvtArgs ea;
  for (int f = 0; f < 15; ++f) ea.E[f] = (const float*)d_in[2 * f + 1];
  ecvt_kernel<<<(EBF_TOTAL + 255) / 256, 256, 0, stream>>>(ea, ebf);

  TprepArgs ta;
  {
    const int foldf[8] = {3, 4, 5, 7, 8, 9, 10, 13};
    for (int g = 0; g < 8; ++g) ta.E[g] = (const float*)d_in[2 * foldf[g] + 1];
  }
  tprep_kernel<<<(92 * 1024 + 255) / 256, 256, 0, stream>>>(ta, W1, T);

  G1Args g1;
  for (int f = 0; f < 15; ++f) g1.idx[f] = (const int*)d_in[2 * f];
  const int* idx_u = (const int*)d_in[30];
  const float* E_u = (const float*)d_in[31];

  const int gm = Bc / 256;
  for (int c = 0; c < nc; ++c) {
    G1Args g1c = g1;
    for (int f = 0; f < 15; ++f) g1c.idx[f] = g1.idx[f] + c * Bc;
    pool_kernel<<<Bc / 16, 512, 0, stream>>>(idx_u, E_u, P, c * Bc);
    gemm1g<<<gm * (1024 / 256), 512, 117824, stream>>>(g1c, ebf, P, T, W1t, b1, H1, 1024, gm);
    gemm8<<<gm * (512 / 256), 512, 98304, stream>>>(H1, W2t, b2, H2, Bc, 512, 1024, gm);
    gemm3f<<<Bc / 128, 512, 0, stream>>>(H2, W3t, b3, W4, b4,
                                         (float*)d_out + (size_t)c * Bc * 2, Bc / 128);
  }
}

// Round 24
// 369.680 us; speedup vs baseline: 1.6626x; 1.3643x over previous
//
#include <hip/hip_runtime.h>
#include <stdint.h>

typedef unsigned short u16;
typedef __attribute__((ext_vector_type(8))) __bf16 bf16x8;
typedef __attribute__((ext_vector_type(4))) float f32x4;

#define B_TOTAL 65536
#define KPAD1   1440   // 1424 padded (pooled feature padded to 128 cols)

__device__ __forceinline__ u16 f2bf(float f) {
  union { float f; uint32_t u; } v; v.f = f;
  uint32_t r = v.u + 0x7fffu + ((v.u >> 16) & 1u);
  return (u16)(r >> 16);
}
__device__ __forceinline__ float bf2f(u16 h) {
  union { uint32_t u; float f; } v; v.u = ((uint32_t)h) << 16;
  return v.f;
}

__device__ __forceinline__ void gload16(const void* g, void* lds) {
  __builtin_amdgcn_global_load_lds(
      (const __attribute__((address_space(1))) uint32_t*)g,
      (__attribute__((address_space(3))) uint32_t*)lds, 16, 0, 0);
}

constexpr int FDIM[15] = {128,128,128,16,16,96,144,64,80,64,48,144,96,16,144};
// X column map (pooled userids = feature 15 at col 1312, dim 128 incl zero pad)
__device__ __constant__ int FOFF2[17] = {0,128,256,384,400,416,512,656,720,800,
                                         864,912,1056,1152,1168,1312,1440};
// elem offsets of each bf16 table inside ebf
__device__ __constant__ int EOFF[15] = {0,32768,65536,98304,98336,98368,101728,
                                        155008,155584,157264,158160,158496,
                                        198096,203568,203600};
__device__ __constant__ int FDIMd[15] = {128,128,128,16,16,96,144,64,80,64,48,144,96,16,144};
#define EBF_TOTAL 246080

// ---------------- weight prep: f32 [K][N] -> bf16 [N][Kpad]
__global__ void wprep_kernel(const float* __restrict__ W, u16* __restrict__ Wt,
                             int K, int N, int Kpad) {
  int o = blockIdx.x * 256 + threadIdx.x;
  if (o >= N * Kpad) return;
  int k = o % Kpad;
  int n = o / Kpad;
  float v = (k < K) ? W[(size_t)k * N + n] : 0.0f;
  Wt[o] = f2bf(v);
}

// ---------------- embedding table convert: 15 f32 tables -> one bf16 blob
struct EcvtArgs { const float* E[15]; };
__global__ void ecvt_kernel(EcvtArgs p, u16* __restrict__ ebf) {
  int i = blockIdx.x * 256 + threadIdx.x;
  if (i >= EBF_TOTAL) return;
  int f = 0;
#pragma unroll
  for (int t = 1; t < 15; ++t) if (i >= EOFF[t]) f = t;
  ebf[i] = f2bf(p.E[f][i - EOFF[f]]);
}

// ---------------- pool: userids mean over 50 -> P[Bc][128] bf16 (cols 112..127 = 0)
// 512 threads = 8 waves, each wave handles 2 rows (16 rows/block)
__global__ __launch_bounds__(512) void pool_kernel(const int* __restrict__ idx_u,
                                                   const float* __restrict__ E_u,
                                                   u16* __restrict__ P, int row_base) {
  __shared__ float eu_t[69 * 112];
  const int tid = threadIdx.x;
  {
    const float4* s4 = reinterpret_cast<const float4*>(E_u);
    float4* d4 = reinterpret_cast<float4*>(eu_t);
    for (int i = tid; i < 69 * 28; i += 512) d4[i] = s4[i];
  }
  const int lane = tid & 63;
  const int wv   = tid >> 6;
  const int row0 = blockIdx.x * 16 + wv * 2;

  const int* iu0 = idx_u + (size_t)(row_base + row0) * 50;
  const int myid0 = (lane < 50) ? iu0[lane] : 0;
  const int myid1 = (lane < 50) ? iu0[50 + lane] : 0;
  __syncthreads();

  const int half = lane >> 5;
  const int c    = lane & 31;

  auto POOL = [&](int myid, u16* prow) {
    if (c < 28) {
      float4 s = {0.f, 0.f, 0.f, 0.f};
      const float* eu = eu_t + c * 4;
      const int j0 = half * 25;
#pragma unroll
      for (int jb = 0; jb < 25; jb += 5) {
        float4 v0, v1, v2, v3, v4;
        {
          const int i0 = __shfl(myid, j0 + jb + 0);
          const int i1 = __shfl(myid, j0 + jb + 1);
          const int i2 = __shfl(myid, j0 + jb + 2);
          const int i3 = __shfl(myid, j0 + jb + 3);
          const int i4 = __shfl(myid, j0 + jb + 4);
          v0 = *reinterpret_cast<const float4*>(eu + i0 * 112);
          v1 = *reinterpret_cast<const float4*>(eu + i1 * 112);
          v2 = *reinterpret_cast<const float4*>(eu + i2 * 112);
          v3 = *reinterpret_cast<const float4*>(eu + i3 * 112);
          v4 = *reinterpret_cast<const float4*>(eu + i4 * 112);
        }
        s.x += v0.x + v1.x + v2.x + v3.x + v4.x;
        s.y += v0.y + v1.y + v2.y + v3.y + v4.y;
        s.z += v0.z + v1.z + v2.z + v3.z + v4.z;
        s.w += v0.w + v1.w + v2.w + v3.w + v4.w;
      }
      s.x += __shfl_xor(s.x, 32);
      s.y += __shfl_xor(s.y, 32);
      s.z += __shfl_xor(s.z, 32);
      s.w += __shfl_xor(s.w, 32);
      if (half == 0) {
        const float inv = 1.0f / 50.0f;
        ushort4 o;
        o.x = f2bf(s.x * inv);
        o.y = f2bf(s.y * inv);
        o.z = f2bf(s.z * inv);
        o.w = f2bf(s.w * inv);
        *reinterpret_cast<ushort4*>(prow + c * 4) = o;
      }
    } else if (half == 1) {
      ushort4 z; z.x = 0; z.y = 0; z.z = 0; z.w = 0;
      *reinterpret_cast<ushort4*>(prow + 112 + (c - 28) * 4) = z;
    }
  };

  POOL(myid0, P + (size_t)row0 * 128);
  POOL(myid1, P + (size_t)(row0 + 1) * 128);
}

// ---------------- gemm1g: GEMM1 with gather-on-stage A (no X buffer)
// LDS byte map: [0,98304) tile bufs | [98304,101184) desc (180x16B) |
//               [101184,118592) idxl (256x17 ints, odd stride = no bank conflict)
#define TILE_ELE 16384

struct G1Args { const int* idx[15]; };

__global__ __launch_bounds__(512, 2) void gemm1g(
    G1Args p, const u16* __restrict__ ebf, const u16* __restrict__ P,
    const u16* __restrict__ Wt, const float* __restrict__ bias,
    u16* __restrict__ C, int N, int gm) {
  constexpr int K = KPAD1;
  constexpr int NT = K / 32;   // 45
  extern __shared__ __align__(16) u16 lds[];
  uint32_t* desc32 = reinterpret_cast<uint32_t*>(&lds[49152]);   // byte 98304, 2880 B
  int* idxl = reinterpret_cast<int*>(&lds[49152 + 1440]);        // byte 101184, 17408 B
  const int tid  = threadIdx.x;
  const int w    = tid >> 6;
  const int lane = tid & 63;
  const int fr   = lane & 15;
  const int kg   = lane >> 4;
  const int wm   = w >> 2;
  const int wn   = w & 3;

  const int nwg = gridDim.x;
  const int q = nwg >> 3, r = nwg & 7;
  const int xcd = blockIdx.x & 7, lid = blockIdx.x >> 3;
  const int swz = (xcd < r) ? (xcd * (q + 1) + lid) : (r * (q + 1) + (xcd - r) * q + lid);
  const int gn = N >> 8;
  const int bn = swz % gn, bm = swz / gn;
  const int rowBase = bm * 256, colBase = bn * 256;

  // ---- preload descriptors + idx table
  if (tid < 180) {
    const int c0 = tid * 8;
    int f = 0;
#pragma unroll
    for (int t = 1; t < 16; ++t) if (c0 >= FOFF2[t]) f = t;
    const u16* base = (f < 15) ? (ebf + EOFF[f]) : P;
    const int dim = (f < 15) ? FDIMd[f] : 128;
    const int off = c0 - FOFF2[f];
    desc32[tid * 4 + 0] = (uint32_t)(uintptr_t)base;
    desc32[tid * 4 + 1] = (uint32_t)((uintptr_t)base >> 32);
    desc32[tid * 4 + 2] = (uint32_t)dim;
    desc32[tid * 4 + 3] = (uint32_t)(off | (f << 16));
  }
#pragma unroll
  for (int f = 0; f < 15; ++f)
    if (tid < 256) idxl[tid * 17 + f] = p.idx[f][rowBase + tid];
  if (tid < 256) idxl[tid * 17 + 15] = tid;   // pooled: P is chunk-local
  __syncthreads();

  const int srow  = lane >> 2;
  const int sslot = (lane & 3) ^ ((lane >> 3) & 3);
  const u16* Bsrc0 = Wt + (size_t)(colBase + w * 16 + srow) * K + sslot * 8;
  const size_t rstep = (size_t)128 * K;
  const int r0 = w * 16 + srow;

  f32x4 acc[8][4];
#pragma unroll
  for (int m = 0; m < 8; ++m)
#pragma unroll
    for (int n = 0; n < 4; ++n)
      acc[m][n] = f32x4{0.f, 0.f, 0.f, 0.f};

  const int aslot8 = (kg ^ ((fr >> 1) & 3)) * 8;
  const int ardA = (wm * 128 + fr) * 32 + aslot8;
  const int ardB = (wn * 64 + fr) * 32 + aslot8 + 8192;

  auto stageA = [&](int ldsElemBase, int kt) {
    const int g = kt * 4 + sslot;
    const uint32_t d0 = desc32[g * 4 + 0];
    const uint32_t d1 = desc32[g * 4 + 1];
    const uint32_t d2 = desc32[g * 4 + 2];
    const uint32_t d3 = desc32[g * 4 + 3];
    const u16* base = (const u16*)(((uint64_t)d1 << 32) | (uint64_t)d0);
    const int dim = (int)d2;
    const int off = (int)(d3 & 0xffffu);
    const int fid = (int)(d3 >> 16);
    const int i0 = idxl[r0 * 17 + fid];
    const int i1 = idxl[(r0 + 128) * 17 + fid];
    gload16(base + (size_t)i0 * dim + off, &lds[ldsElemBase + w * 512]);
    gload16(base + (size_t)i1 * dim + off, &lds[ldsElemBase + w * 512 + 4096]);
  };
  auto stageB = [&](int ldsElemBase, int kt) {
    const u16* s = Bsrc0 + (size_t)kt * 32;
    gload16(s,         &lds[ldsElemBase + w * 512]);
    gload16(s + rstep, &lds[ldsElemBase + w * 512 + 4096]);
  };

  stageA(0 * TILE_ELE,        0);
  stageB(0 * TILE_ELE + 8192, 0);
  stageA(1 * TILE_ELE,        1);
  stageB(1 * TILE_ELE + 8192, 1);

  for (int t = 0; t < NT; ++t) {
    const int cb = t % 3;
    const int sb = (t + 2) % 3;
    const bool dost = (t + 2) < NT;
    const int cA = cb * TILE_ELE;

    __builtin_amdgcn_sched_barrier(0);
    if (t < NT - 1) asm volatile("s_waitcnt vmcnt(4)" ::: "memory");
    else            asm volatile("s_waitcnt vmcnt(0)" ::: "memory");
    __builtin_amdgcn_s_barrier();
    __builtin_amdgcn_sched_barrier(0);

    if (dost) {
      stageA(sb * TILE_ELE,        t + 2);
      stageB(sb * TILE_ELE + 8192, t + 2);
    }

    bf16x8 a0 = *(const bf16x8*)&lds[cA + ardA + 0 * 512];
    bf16x8 a1 = *(const bf16x8*)&lds[cA + ardA + 1 * 512];
    bf16x8 a2 = *(const bf16x8*)&lds[cA + ardA + 2 * 512];
    bf16x8 a3 = *(const bf16x8*)&lds[cA + ardA + 3 * 512];
    bf16x8 b0 = *(const bf16x8*)&lds[cA + ardB + 0 * 512];
    bf16x8 b1 = *(const bf16x8*)&lds[cA + ardB + 1 * 512];
    bf16x8 b2 = *(const bf16x8*)&lds[cA + ardB + 2 * 512];
    bf16x8 b3 = *(const bf16x8*)&lds[cA + ardB + 3 * 512];
    bf16x8 c0 = *(const bf16x8*)&lds[cA + ardA + 2048 + 0 * 512];
    bf16x8 c1 = *(const bf16x8*)&lds[cA + ardA + 2048 + 1 * 512];
    bf16x8 c2 = *(const bf16x8*)&lds[cA + ardA + 2048 + 2 * 512];
    bf16x8 c3 = *(const bf16x8*)&lds[cA + ardA + 2048 + 3 * 512];
#pragma unroll
    for (int n = 0; n < 4; ++n) {
      bf16x8 bf = (n == 0) ? b0 : (n == 1) ? b1 : (n == 2) ? b2 : b3;
      acc[0][n] = __builtin_amdgcn_mfma_f32_16x16x32_bf16(bf, a0, acc[0][n], 0, 0, 0);
      acc[1][n] = __builtin_amdgcn_mfma_f32_16x16x32_bf16(bf, a1, acc[1][n], 0, 0, 0);
      acc[2][n] = __builtin_amdgcn_mfma_f32_16x16x32_bf16(bf, a2, acc[2][n], 0, 0, 0);
      acc[3][n] = __builtin_amdgcn_mfma_f32_16x16x32_bf16(bf, a3, acc[3][n], 0, 0, 0);
      acc[4][n] = __builtin_amdgcn_mfma_f32_16x16x32_bf16(bf, c0, acc[4][n], 0, 0, 0);
      acc[5][n] = __builtin_amdgcn_mfma_f32_16x16x32_bf16(bf, c1, acc[5][n], 0, 0, 0);
      acc[6][n] = __builtin_amdgcn_mfma_f32_16x16x32_bf16(bf, c2, acc[6][n], 0, 0, 0);
      acc[7][n] = __builtin_amdgcn_mfma_f32_16x16x32_bf16(bf, c3, acc[7][n], 0, 0, 0);
    }
  }

#pragma unroll
  for (int mm = 0; mm < 8; ++mm) {
    const int row = rowBase + wm * 128 + (mm >> 2) * 64 + (mm & 3) * 16 + fr;
#pragma unroll
    for (int n = 0; n < 4; ++n) {
      const int col0 = colBase + wn * 64 + n * 16 + kg * 4;
      ushort4 o;
      o.x = f2bf(fmaxf(acc[mm][n][0] + bias[col0 + 0], 0.f));
      o.y = f2bf(fmaxf(acc[mm][n][1] + bias[col0 + 1], 0.f));
      o.z = f2bf(fmaxf(acc[mm][n][2] + bias[col0 + 2], 0.f));
      o.w = f2bf(fmaxf(acc[mm][n][3] + bias[col0 + 3], 0.f));
      *reinterpret_cast<ushort4*>(&C[(size_t)row * N + col0]) = o;
    }
  }
}

// ---------------- gemm8: R15 version (3-buffer counted vmcnt + bn-fast swizzle)
__global__ __launch_bounds__(512, 2) void gemm8(
    const u16* __restrict__ A, const u16* __restrict__ Wt,
    const float* __restrict__ bias, u16* __restrict__ C,
    int M, int N, int K, int gm) {
  extern __shared__ __align__(16) u16 lds[];
  const int tid  = threadIdx.x;
  const int w    = tid >> 6;
  const int lane = tid & 63;
  const int fr   = lane & 15;
  const int kg   = lane >> 4;
  const int wm   = w >> 2;
  const int wn   = w & 3;

  const int nwg = gridDim.x;
  const int q = nwg >> 3, r = nwg & 7;
  const int xcd = blockIdx.x & 7, lid = blockIdx.x >> 3;
  const int swz = (xcd < r) ? (xcd * (q + 1) + lid) : (r * (q + 1) + (xcd - r) * q + lid);
  const int gn = N >> 8;
  const int bn = swz % gn, bm = swz / gn;
  const int rowBase = bm * 256, colBase = bn * 256;

  const int srow  = lane >> 2;
  const int sslot = (lane & 3) ^ ((lane >> 3) & 3);
  const u16* Asrc0 = A  + (size_t)(rowBase + w * 16 + srow) * K + sslot * 8;
  const u16* Bsrc0 = Wt + (size_t)(colBase + w * 16 + srow) * K + sslot * 8;
  const size_t rstep = (size_t)128 * K;

  const int NT = K / 32;

  f32x4 acc[8][4];
#pragma unroll
  for (int m = 0; m < 8; ++m)
#pragma unroll
    for (int n = 0; n < 4; ++n)
      acc[m][n] = f32x4{0.f, 0.f, 0.f, 0.f};

  const int aslot8 = (kg ^ ((fr >> 1) & 3)) * 8;
  const int ardA = (wm * 128 + fr) * 32 + aslot8;
  const int ardB = (wn * 64 + fr) * 32 + aslot8 + 8192;

  auto stage = [&](const u16* src0, int ldsElemBase, int kt) {
    const u16* s = src0 + (size_t)kt * 32;
    gload16(s,         &lds[ldsElemBase + w * 512]);
    gload16(s + rstep, &lds[ldsElemBase + w * 512 + 4096]);
  };

  stage(Asrc0, 0 * TILE_ELE,        0);
  stage(Bsrc0, 0 * TILE_ELE + 8192, 0);
  stage(Asrc0, 1 * TILE_ELE,        1);
  stage(Bsrc0, 1 * TILE_ELE + 8192, 1);

  for (int t = 0; t < NT; ++t) {
    const int cb = t % 3;
    const int sb = (t + 2) % 3;
    const bool dost = (t + 2) < NT;
    const int cA = cb * TILE_ELE;

    __builtin_amdgcn_sched_barrier(0);
    if (t < NT - 1) asm volatile("s_waitcnt vmcnt(4)" ::: "memory");
    else            asm volatile("s_waitcnt vmcnt(0)" ::: "memory");
    __builtin_amdgcn_s_barrier();
    __builtin_amdgcn_sched_barrier(0);

    bf16x8 a0 = *(const bf16x8*)&lds[cA + ardA + 0 * 512];
    bf16x8 a1 = *(const bf16x8*)&lds[cA + ardA + 1 * 512];
    bf16x8 a2 = *(const bf16x8*)&lds[cA + ardA + 2 * 512];
    bf16x8 a3 = *(const bf16x8*)&lds[cA + ardA + 3 * 512];
    bf16x8 b0 = *(const bf16x8*)&lds[cA + ardB + 0 * 512];
    bf16x8 b1 = *(const bf16x8*)&lds[cA + ardB + 1 * 512];
    bf16x8 b2 = *(const bf16x8*)&lds[cA + ardB + 2 * 512];
    bf16x8 b3 = *(const bf16x8*)&lds[cA + ardB + 3 * 512];
    bf16x8 c0 = *(const bf16x8*)&lds[cA + ardA + 2048 + 0 * 512];
    bf16x8 c1 = *(const bf16x8*)&lds[cA + ardA + 2048 + 1 * 512];
    bf16x8 c2 = *(const bf16x8*)&lds[cA + ardA + 2048 + 2 * 512];
    bf16x8 c3 = *(const bf16x8*)&lds[cA + ardA + 2048 + 3 * 512];
    if (dost) {
      stage(Asrc0, sb * TILE_ELE,        t + 2);
      stage(Bsrc0, sb * TILE_ELE + 8192, t + 2);
    }
#pragma unroll
    for (int n = 0; n < 4; ++n) {
      bf16x8 bf = (n == 0) ? b0 : (n == 1) ? b1 : (n == 2) ? b2 : b3;
      acc[0][n] = __builtin_amdgcn_mfma_f32_16x16x32_bf16(bf, a0, acc[0][n], 0, 0, 0);
      acc[1][n] = __builtin_amdgcn_mfma_f32_16x16x32_bf16(bf, a1, acc[1][n], 0, 0, 0);
      acc[2][n] = __builtin_amdgcn_mfma_f32_16x16x32_bf16(bf, a2, acc[2][n], 0, 0, 0);
      acc[3][n] = __builtin_amdgcn_mfma_f32_16x16x32_bf16(bf, a3, acc[3][n], 0, 0, 0);
      acc[4][n] = __builtin_amdgcn_mfma_f32_16x16x32_bf16(bf, c0, acc[4][n], 0, 0, 0);
      acc[5][n] = __builtin_amdgcn_mfma_f32_16x16x32_bf16(bf, c1, acc[5][n], 0, 0, 0);
      acc[6][n] = __builtin_amdgcn_mfma_f32_16x16x32_bf16(bf, c2, acc[6][n], 0, 0, 0);
      acc[7][n] = __builtin_amdgcn_mfma_f32_16x16x32_bf16(bf, c3, acc[7][n], 0, 0, 0);
    }
  }

#pragma unroll
  for (int mm = 0; mm < 8; ++mm) {
    const int row = rowBase + wm * 128 + (mm >> 2) * 64 + (mm & 3) * 16 + fr;
#pragma unroll
    for (int n = 0; n < 4; ++n) {
      const int col0 = colBase + wn * 64 + n * 16 + kg * 4;
      ushort4 o;
      o.x = f2bf(fmaxf(acc[mm][n][0] + bias[col0 + 0], 0.f));
      o.y = f2bf(fmaxf(acc[mm][n][1] + bias[col0 + 1], 0.f));
      o.z = f2bf(fmaxf(acc[mm][n][2] + bias[col0 + 2], 0.f));
      o.w = f2bf(fmaxf(acc[mm][n][3] + bias[col0 + 3], 0.f));
      *reinterpret_cast<ushort4*>(&C[(size_t)row * N + col0]) = o;
    }
  }
}

// ---------------- gemm3f: fused GEMM3 (128x256 tile, K=512) + W4 GEMV + softmax
__global__ __launch_bounds__(512, 2) void gemm3f(
    const u16* __restrict__ A, const u16* __restrict__ Wt,
    const float* __restrict__ bias, const float* __restrict__ W4,
    const float* __restrict__ b4, float* __restrict__ out, int gm) {
  constexpr int K = 512, NT = 16;
  __shared__ __align__(16) u16 lds[2][12288];
  __shared__ float w4s[512];
  __shared__ float zred[4][128][2];
  const int tid  = threadIdx.x;
  const int w    = tid >> 6;
  const int lane = tid & 63;
  const int fr   = lane & 15;
  const int kg   = lane >> 4;
  const int wm   = w >> 2;
  const int wn   = w & 3;

  const int nwg = gridDim.x;
  const int q = nwg >> 3, r = nwg & 7;
  const int xcd = blockIdx.x & 7, lid = blockIdx.x >> 3;
  const int swz = (xcd < r) ? (xcd * (q + 1) + lid) : (r * (q + 1) + (xcd - r) * q + lid);
  const int rowBase = swz * 128;

  if (tid < 512) w4s[tid] = W4[tid];

  const int xslot = (tid & 3) ^ ((tid >> 3) & 3);
  const u16* Asrc  = A  + (size_t)(rowBase + (tid >> 2)) * K + xslot * 8;
  const u16* Bsrc0 = Wt + (size_t)(tid >> 2) * K + xslot * 8;
  const u16* Bsrc1 = Wt + (size_t)((tid >> 2) + 128) * K + xslot * 8;

  auto stage = [&](int buf, int kt) {
    const int ko = kt * 32;
    gload16(Asrc  + ko, &lds[buf][tid * 8]);
    gload16(Bsrc0 + ko, &lds[buf][4096 + tid * 8]);
    gload16(Bsrc1 + ko, &lds[buf][8192 + tid * 8]);
  };

  f32x4 acc[4][4];
#pragma unroll
  for (int m = 0; m < 4; ++m)
#pragma unroll
    for (int n = 0; n < 4; ++n)
      acc[m][n] = f32x4{0.f, 0.f, 0.f, 0.f};

  const int aslot8 = (kg ^ ((fr >> 1) & 3)) * 8;
  const int ardA = (wm * 64 + fr) * 32 + aslot8;
  const int ardB = 4096 + (wn * 64 + fr) * 32 + aslot8;

  stage(0, 0);
  stage(1, 1);

  for (int t = 0; t < NT; ++t) {
    const int cb = t & 1;
    if (t < NT - 1) asm volatile("s_waitcnt vmcnt(3)" ::: "memory");
    else            asm volatile("s_waitcnt vmcnt(0)" ::: "memory");
    __builtin_amdgcn_s_barrier();

    bf16x8 a0 = *(const bf16x8*)&lds[cb][ardA + 0 * 512];
    bf16x8 a1 = *(const bf16x8*)&lds[cb][ardA + 1 * 512];
    bf16x8 a2 = *(const bf16x8*)&lds[cb][ardA + 2 * 512];
    bf16x8 a3 = *(const bf16x8*)&lds[cb][ardA + 3 * 512];
    bf16x8 b0 = *(const bf16x8*)&lds[cb][ardB + 0 * 512];
    bf16x8 b1 = *(const bf16x8*)&lds[cb][ardB + 1 * 512];
    bf16x8 b2 = *(const bf16x8*)&lds[cb][ardB + 2 * 512];
    bf16x8 b3 = *(const bf16x8*)&lds[cb][ardB + 3 * 512];
    asm volatile("s_waitcnt lgkmcnt(0)" ::: "memory");
    __builtin_amdgcn_s_barrier();
    if (t + 2 < NT) stage(cb, t + 2);
    __builtin_amdgcn_sched_barrier(0);
    __builtin_amdgcn_s_setprio(1);
#pragma unroll
    for (int n = 0; n < 4; ++n) {
      bf16x8 bf = (n == 0) ? b0 : (n == 1) ? b1 : (n == 2) ? b2 : b3;
      acc[0][n] = __builtin_amdgcn_mfma_f32_16x16x32_bf16(bf, a0, acc[0][n], 0, 0, 0);
      acc[1][n] = __builtin_amdgcn_mfma_f32_16x16x32_bf16(bf, a1, acc[1][n], 0, 0, 0);
      acc[2][n] = __builtin_amdgcn_mfma_f32_16x16x32_bf16(bf, a2, acc[2][n], 0, 0, 0);
      acc[3][n] = __builtin_amdgcn_mfma_f32_16x16x32_bf16(bf, a3, acc[3][n], 0, 0, 0);
    }
    __builtin_amdgcn_s_setprio(0);
  }

  float z0[4] = {0.f, 0.f, 0.f, 0.f};
  float z1[4] = {0.f, 0.f, 0.f, 0.f};
#pragma unroll
  for (int n = 0; n < 4; ++n) {
    const int col0 = wn * 64 + n * 16 + kg * 4;
#pragma unroll
    for (int j = 0; j < 4; ++j) {
      const int c = col0 + j;
      const float bv = bias[c];
      const float w40 = w4s[c * 2];
      const float w41 = w4s[c * 2 + 1];
#pragma unroll
      for (int m = 0; m < 4; ++m) {
        const float h = fmaxf(acc[m][n][j] + bv, 0.f);
        z0[m] += h * w40;
        z1[m] += h * w41;
      }
    }
  }
#pragma unroll
  for (int m = 0; m < 4; ++m) {
    z0[m] += __shfl_xor(z0[m], 16); z0[m] += __shfl_xor(z0[m], 32);
    z1[m] += __shfl_xor(z1[m], 16); z1[m] += __shfl_xor(z1[m], 32);
  }
  if (kg == 0) {
#pragma unroll
    for (int m = 0; m < 4; ++m) {
      const int rr = wm * 64 + m * 16 + fr;
      zred[wn][rr][0] = z0[m];
      zred[wn][rr][1] = z1[m];
    }
  }
  __syncthreads();
  if (tid < 128) {
    const float s0 = zred[0][tid][0] + zred[1][tid][0] + zred[2][tid][0] + zred[3][tid][0];
    const float s1 = zred[0][tid][1] + zred[1][tid][1] + zred[2][tid][1] + zred[3][tid][1];
    const float zz0 = fmaxf(s0 + b4[0], 0.f);
    const float zz1 = fmaxf(s1 + b4[1], 0.f);
    const float mx = fmaxf(zz0, zz1);
    const float e0 = __expf(zz0 - mx), e1 = __expf(zz1 - mx);
    const float inv = 1.0f / (e0 + e1);
    out[(size_t)(rowBase + tid) * 2]     = e0 * inv;
    out[(size_t)(rowBase + tid) * 2 + 1] = e1 * inv;
  }
}

// ---------------- host side
extern "C" void kernel_launch(void* const* d_in, const int* in_sizes, int n_in,
                              void* d_out, int out_size, void* d_ws, size_t ws_size,
                              hipStream_t stream) {
  const float* W1 = (const float*)d_in[32];
  const float* b1 = (const float*)d_in[33];
  const float* W2 = (const float*)d_in[34];
  const float* b2 = (const float*)d_in[35];
  const float* W3 = (const float*)d_in[36];
  const float* b3 = (const float*)d_in[37];
  const float* W4 = (const float*)d_in[38];
  const float* b4 = (const float*)d_in[39];

  (void)hipFuncSetAttribute(reinterpret_cast<const void*>(&gemm8),
                            hipFuncAttributeMaxDynamicSharedMemorySize, 98304);
  (void)hipFuncSetAttribute(reinterpret_cast<const void*>(&gemm1g),
                            hipFuncAttributeMaxDynamicSharedMemorySize, 118784);

  char* ws = (char*)d_ws;
  size_t off = 0;
  auto alloc = [&](size_t bytes) -> void* {
    void* p = ws + off;
    off += (bytes + 255) & ~(size_t)255;
    return p;
  };

  u16* W1t = (u16*)alloc((size_t)1024 * KPAD1 * 2);
  u16* W2t = (u16*)alloc((size_t)512 * 1024 * 2);
  u16* W3t = (u16*)alloc((size_t)256 * 512 * 2);
  u16* ebf = (u16*)alloc((size_t)EBF_TOTAL * 2);
  const size_t fixed = off;

  // per-chunk: P (Bc x 128) + H1 (Bc x 1024) + H2 (Bc x 512), bf16
  int nc = 64;
  const int cands[7] = {1, 2, 4, 8, 16, 32, 64};
  for (int ci = 0; ci < 7; ++ci) {
    size_t Bc = (size_t)B_TOTAL / cands[ci];
    size_t need = fixed + Bc * (128 + 1024 + 512) * 2 + 4096;
    if (need <= ws_size) { nc = cands[ci]; break; }
  }
  const int Bc = B_TOTAL / nc;

  u16* P  = (u16*)alloc((size_t)Bc * 128 * 2);
  u16* H1 = (u16*)alloc((size_t)Bc * 1024 * 2);
  u16* H2 = (u16*)alloc((size_t)Bc * 512 * 2);

  wprep_kernel<<<(1024 * KPAD1 + 255) / 256, 256, 0, stream>>>(W1, W1t, 1424, 1024, KPAD1);
  wprep_kernel<<<(512 * 1024 + 255) / 256, 256, 0, stream>>>(W2, W2t, 1024, 512, 1024);
  wprep_kernel<<<(256 * 512 + 255) / 256, 256, 0, stream>>>(W3, W3t, 512, 256, 512);

  EcvtArgs ea;
  for (int f = 0; f < 15; ++f) ea.E[f] = (const float*)d_in[2 * f + 1];
  ecvt_kernel<<<(EBF_TOTAL + 255) / 256, 256, 0, stream>>>(ea, ebf);

  G1Args g1;
  for (int f = 0; f < 15; ++f) g1.idx[f] = (const int*)d_in[2 * f];
  const int* idx_u = (const int*)d_in[30];
  const float* E_u = (const float*)d_in[31];

  const int gm = Bc / 256;
  for (int c = 0; c < nc; ++c) {
    G1Args g1c = g1;
    for (int f = 0; f < 15; ++f) g1c.idx[f] = g1.idx[f] + c * Bc;
    pool_kernel<<<Bc / 16, 512, 0, stream>>>(idx_u, E_u, P, c * Bc);
    gemm1g<<<gm * (1024 / 256), 512, 118784, stream>>>(g1c, ebf, P, W1t, b1, H1, 1024, gm);
    gemm8<<<gm * (512 / 256), 512, 98304, stream>>>(H1, W2t, b2, H2, Bc, 512, 1024, gm);
    gemm3f<<<Bc / 128, 512, 0, stream>>>(H2, W3t, b3, W4, b4,
                                         (float*)d_out + (size_t)c * Bc * 2, Bc / 128);
  }
}

// Round 25
// 365.337 us; speedup vs baseline: 1.6824x; 1.0119x over previous
//
#include <hip/hip_runtime.h>
#include <stdint.h>

typedef unsigned short u16;
typedef __attribute__((ext_vector_type(8))) __bf16 bf16x8;
typedef __attribute__((ext_vector_type(4))) float f32x4;

#define B_TOTAL 65536
#define KPAD1   1440   // 1424 padded (pooled feature padded to 128 cols)

__device__ __forceinline__ u16 f2bf(float f) {
  union { float f; uint32_t u; } v; v.f = f;
  uint32_t r = v.u + 0x7fffu + ((v.u >> 16) & 1u);
  return (u16)(r >> 16);
}
__device__ __forceinline__ float bf2f(u16 h) {
  union { uint32_t u; float f; } v; v.u = ((uint32_t)h) << 16;
  return v.f;
}

__device__ __forceinline__ void gload16(const void* g, void* lds) {
  __builtin_amdgcn_global_load_lds(
      (const __attribute__((address_space(1))) uint32_t*)g,
      (__attribute__((address_space(3))) uint32_t*)lds, 16, 0, 0);
}

constexpr int FDIM[15] = {128,128,128,16,16,96,144,64,80,64,48,144,96,16,144};
// X column map (pooled userids = feature 15 at col 1312, dim 128 incl zero pad)
__device__ __constant__ int FOFF2[17] = {0,128,256,384,400,416,512,656,720,800,
                                         864,912,1056,1152,1168,1312,1440};
// elem offsets of each bf16 table inside ebf
__device__ __constant__ int EOFF[15] = {0,32768,65536,98304,98336,98368,101728,
                                        155008,155584,157264,158160,158496,
                                        198096,203568,203600};
__device__ __constant__ int FDIMd[15] = {128,128,128,16,16,96,144,64,80,64,48,144,96,16,144};
#define EBF_TOTAL 246080

// ---------------- weight prep (tiled transpose): f32 W[K][N] -> bf16 Wt[N][Kpad]
// Old version read W with stride-N per lane (16x sector over-fetch, ~135 MB).
// 32x32 LDS tile: read coalesced along n, write coalesced along k.
__global__ __launch_bounds__(256) void wprepT_kernel(const float* __restrict__ W,
                                                     u16* __restrict__ Wt,
                                                     int K, int N, int Kpad) {
  __shared__ u16 t[32][33];
  const int kb = blockIdx.x * 32;
  const int nb = blockIdx.y * 32;
  const int lx = threadIdx.x & 31;
  const int ly = threadIdx.x >> 5;   // 0..7
#pragma unroll
  for (int dy = 0; dy < 32; dy += 8) {
    const int k = kb + ly + dy;
    const int n = nb + lx;
    const float v = (k < K) ? W[(size_t)k * N + n] : 0.0f;   // coalesced (n fast)
    t[ly + dy][lx] = f2bf(v);
  }
  __syncthreads();
#pragma unroll
  for (int dy = 0; dy < 32; dy += 8) {
    const int n = nb + ly + dy;
    const int k = kb + lx;
    Wt[(size_t)n * Kpad + k] = t[lx][ly + dy];               // coalesced (k fast)
  }
}

// ---------------- embedding table convert: 15 f32 tables -> one bf16 blob
struct EcvtArgs { const float* E[15]; };
__global__ void ecvt_kernel(EcvtArgs p, u16* __restrict__ ebf) {
  int i = blockIdx.x * 256 + threadIdx.x;
  if (i >= EBF_TOTAL) return;
  int f = 0;
#pragma unroll
  for (int t = 1; t < 15; ++t) if (i >= EOFF[t]) f = t;
  ebf[i] = f2bf(p.E[f][i - EOFF[f]]);
}

// ---------------- pool: userids mean over 50 -> P[Bc][128] bf16 (cols 112..127 = 0)
// 512 threads = 8 waves, each wave handles 2 rows (16 rows/block)
__global__ __launch_bounds__(512) void pool_kernel(const int* __restrict__ idx_u,
                                                   const float* __restrict__ E_u,
                                                   u16* __restrict__ P, int row_base) {
  __shared__ float eu_t[69 * 112];
  const int tid = threadIdx.x;
  {
    const float4* s4 = reinterpret_cast<const float4*>(E_u);
    float4* d4 = reinterpret_cast<float4*>(eu_t);
    for (int i = tid; i < 69 * 28; i += 512) d4[i] = s4[i];
  }
  const int lane = tid & 63;
  const int wv   = tid >> 6;
  const int row0 = blockIdx.x * 16 + wv * 2;

  const int* iu0 = idx_u + (size_t)(row_base + row0) * 50;
  const int myid0 = (lane < 50) ? iu0[lane] : 0;
  const int myid1 = (lane < 50) ? iu0[50 + lane] : 0;
  __syncthreads();

  const int half = lane >> 5;
  const int c    = lane & 31;

  auto POOL = [&](int myid, u16* prow) {
    if (c < 28) {
      float4 s = {0.f, 0.f, 0.f, 0.f};
      const float* eu = eu_t + c * 4;
      const int j0 = half * 25;
#pragma unroll
      for (int jb = 0; jb < 25; jb += 5) {
        float4 v0, v1, v2, v3, v4;
        {
          const int i0 = __shfl(myid, j0 + jb + 0);
          const int i1 = __shfl(myid, j0 + jb + 1);
          const int i2 = __shfl(myid, j0 + jb + 2);
          const int i3 = __shfl(myid, j0 + jb + 3);
          const int i4 = __shfl(myid, j0 + jb + 4);
          v0 = *reinterpret_cast<const float4*>(eu + i0 * 112);
          v1 = *reinterpret_cast<const float4*>(eu + i1 * 112);
          v2 = *reinterpret_cast<const float4*>(eu + i2 * 112);
          v3 = *reinterpret_cast<const float4*>(eu + i3 * 112);
          v4 = *reinterpret_cast<const float4*>(eu + i4 * 112);
        }
        s.x += v0.x + v1.x + v2.x + v3.x + v4.x;
        s.y += v0.y + v1.y + v2.y + v3.y + v4.y;
        s.z += v0.z + v1.z + v2.z + v3.z + v4.z;
        s.w += v0.w + v1.w + v2.w + v3.w + v4.w;
      }
      s.x += __shfl_xor(s.x, 32);
      s.y += __shfl_xor(s.y, 32);
      s.z += __shfl_xor(s.z, 32);
      s.w += __shfl_xor(s.w, 32);
      if (half == 0) {
        const float inv = 1.0f / 50.0f;
        ushort4 o;
        o.x = f2bf(s.x * inv);
        o.y = f2bf(s.y * inv);
        o.z = f2bf(s.z * inv);
        o.w = f2bf(s.w * inv);
        *reinterpret_cast<ushort4*>(prow + c * 4) = o;
      }
    } else if (half == 1) {
      ushort4 z; z.x = 0; z.y = 0; z.z = 0; z.w = 0;
      *reinterpret_cast<ushort4*>(prow + 112 + (c - 28) * 4) = z;
    }
  };

  POOL(myid0, P + (size_t)row0 * 128);
  POOL(myid1, P + (size_t)(row0 + 1) * 128);
}

// ---------------- gemm1g: GEMM1 with gather-on-stage A (no X buffer)
// LDS byte map: [0,98304) tile bufs | [98304,101184) desc (180x16B) |
//               [101184,118592) idxl (256x17 ints, odd stride = no bank conflict)
#define TILE_ELE 16384

struct G1Args { const int* idx[15]; };

__global__ __launch_bounds__(512, 2) void gemm1g(
    G1Args p, const u16* __restrict__ ebf, const u16* __restrict__ P,
    const u16* __restrict__ Wt, const float* __restrict__ bias,
    u16* __restrict__ C, int N, int gm) {
  constexpr int K = KPAD1;
  constexpr int NT = K / 32;   // 45
  extern __shared__ __align__(16) u16 lds[];
  uint32_t* desc32 = reinterpret_cast<uint32_t*>(&lds[49152]);   // byte 98304, 2880 B
  int* idxl = reinterpret_cast<int*>(&lds[49152 + 1440]);        // byte 101184, 17408 B
  const int tid  = threadIdx.x;
  const int w    = tid >> 6;
  const int lane = tid & 63;
  const int fr   = lane & 15;
  const int kg   = lane >> 4;
  const int wm   = w >> 2;
  const int wn   = w & 3;

  const int nwg = gridDim.x;
  const int q = nwg >> 3, r = nwg & 7;
  const int xcd = blockIdx.x & 7, lid = blockIdx.x >> 3;
  const int swz = (xcd < r) ? (xcd * (q + 1) + lid) : (r * (q + 1) + (xcd - r) * q + lid);
  const int gn = N >> 8;
  const int bn = swz % gn, bm = swz / gn;
  const int rowBase = bm * 256, colBase = bn * 256;

  // ---- preload descriptors + idx table
  if (tid < 180) {
    const int c0 = tid * 8;
    int f = 0;
#pragma unroll
    for (int t = 1; t < 16; ++t) if (c0 >= FOFF2[t]) f = t;
    const u16* base = (f < 15) ? (ebf + EOFF[f]) : P;
    const int dim = (f < 15) ? FDIMd[f] : 128;
    const int off = c0 - FOFF2[f];
    desc32[tid * 4 + 0] = (uint32_t)(uintptr_t)base;
    desc32[tid * 4 + 1] = (uint32_t)((uintptr_t)base >> 32);
    desc32[tid * 4 + 2] = (uint32_t)dim;
    desc32[tid * 4 + 3] = (uint32_t)(off | (f << 16));
  }
#pragma unroll
  for (int f = 0; f < 15; ++f)
    if (tid < 256) idxl[tid * 17 + f] = p.idx[f][rowBase + tid];
  if (tid < 256) idxl[tid * 17 + 15] = tid;   // pooled: P is chunk-local
  __syncthreads();

  const int srow  = lane >> 2;
  const int sslot = (lane & 3) ^ ((lane >> 3) & 3);
  const u16* Bsrc0 = Wt + (size_t)(colBase + w * 16 + srow) * K + sslot * 8;
  const size_t rstep = (size_t)128 * K;
  const int r0 = w * 16 + srow;

  f32x4 acc[8][4];
#pragma unroll
  for (int m = 0; m < 8; ++m)
#pragma unroll
    for (int n = 0; n < 4; ++n)
      acc[m][n] = f32x4{0.f, 0.f, 0.f, 0.f};

  const int aslot8 = (kg ^ ((fr >> 1) & 3)) * 8;
  const int ardA = (wm * 128 + fr) * 32 + aslot8;
  const int ardB = (wn * 64 + fr) * 32 + aslot8 + 8192;

  auto stageA = [&](int ldsElemBase, int kt) {
    const int g = kt * 4 + sslot;
    const uint32_t d0 = desc32[g * 4 + 0];
    const uint32_t d1 = desc32[g * 4 + 1];
    const uint32_t d2 = desc32[g * 4 + 2];
    const uint32_t d3 = desc32[g * 4 + 3];
    const u16* base = (const u16*)(((uint64_t)d1 << 32) | (uint64_t)d0);
    const int dim = (int)d2;
    const int off = (int)(d3 & 0xffffu);
    const int fid = (int)(d3 >> 16);
    const int i0 = idxl[r0 * 17 + fid];
    const int i1 = idxl[(r0 + 128) * 17 + fid];
    gload16(base + (size_t)i0 * dim + off, &lds[ldsElemBase + w * 512]);
    gload16(base + (size_t)i1 * dim + off, &lds[ldsElemBase + w * 512 + 4096]);
  };
  auto stageB = [&](int ldsElemBase, int kt) {
    const u16* s = Bsrc0 + (size_t)kt * 32;
    gload16(s,         &lds[ldsElemBase + w * 512]);
    gload16(s + rstep, &lds[ldsElemBase + w * 512 + 4096]);
  };

  stageA(0 * TILE_ELE,        0);
  stageB(0 * TILE_ELE + 8192, 0);
  stageA(1 * TILE_ELE,        1);
  stageB(1 * TILE_ELE + 8192, 1);

  for (int t = 0; t < NT; ++t) {
    const int cb = t % 3;
    const int sb = (t + 2) % 3;
    const bool dost = (t + 2) < NT;
    const int cA = cb * TILE_ELE;

    __builtin_amdgcn_sched_barrier(0);
    if (t < NT - 1) asm volatile("s_waitcnt vmcnt(4)" ::: "memory");
    else            asm volatile("s_waitcnt vmcnt(0)" ::: "memory");
    __builtin_amdgcn_s_barrier();
    __builtin_amdgcn_sched_barrier(0);

    if (dost) {
      stageA(sb * TILE_ELE,        t + 2);
      stageB(sb * TILE_ELE + 8192, t + 2);
    }

    bf16x8 a0 = *(const bf16x8*)&lds[cA + ardA + 0 * 512];
    bf16x8 a1 = *(const bf16x8*)&lds[cA + ardA + 1 * 512];
    bf16x8 a2 = *(const bf16x8*)&lds[cA + ardA + 2 * 512];
    bf16x8 a3 = *(const bf16x8*)&lds[cA + ardA + 3 * 512];
    bf16x8 b0 = *(const bf16x8*)&lds[cA + ardB + 0 * 512];
    bf16x8 b1 = *(const bf16x8*)&lds[cA + ardB + 1 * 512];
    bf16x8 b2 = *(const bf16x8*)&lds[cA + ardB + 2 * 512];
    bf16x8 b3 = *(const bf16x8*)&lds[cA + ardB + 3 * 512];
    bf16x8 c0 = *(const bf16x8*)&lds[cA + ardA + 2048 + 0 * 512];
    bf16x8 c1 = *(const bf16x8*)&lds[cA + ardA + 2048 + 1 * 512];
    bf16x8 c2 = *(const bf16x8*)&lds[cA + ardA + 2048 + 2 * 512];
    bf16x8 c3 = *(const bf16x8*)&lds[cA + ardA + 2048 + 3 * 512];
#pragma unroll
    for (int n = 0; n < 4; ++n) {
      bf16x8 bf = (n == 0) ? b0 : (n == 1) ? b1 : (n == 2) ? b2 : b3;
      acc[0][n] = __builtin_amdgcn_mfma_f32_16x16x32_bf16(bf, a0, acc[0][n], 0, 0, 0);
      acc[1][n] = __builtin_amdgcn_mfma_f32_16x16x32_bf16(bf, a1, acc[1][n], 0, 0, 0);
      acc[2][n] = __builtin_amdgcn_mfma_f32_16x16x32_bf16(bf, a2, acc[2][n], 0, 0, 0);
      acc[3][n] = __builtin_amdgcn_mfma_f32_16x16x32_bf16(bf, a3, acc[3][n], 0, 0, 0);
      acc[4][n] = __builtin_amdgcn_mfma_f32_16x16x32_bf16(bf, c0, acc[4][n], 0, 0, 0);
      acc[5][n] = __builtin_amdgcn_mfma_f32_16x16x32_bf16(bf, c1, acc[5][n], 0, 0, 0);
      acc[6][n] = __builtin_amdgcn_mfma_f32_16x16x32_bf16(bf, c2, acc[6][n], 0, 0, 0);
      acc[7][n] = __builtin_amdgcn_mfma_f32_16x16x32_bf16(bf, c3, acc[7][n], 0, 0, 0);
    }
  }

#pragma unroll
  for (int mm = 0; mm < 8; ++mm) {
    const int row = rowBase + wm * 128 + (mm >> 2) * 64 + (mm & 3) * 16 + fr;
#pragma unroll
    for (int n = 0; n < 4; ++n) {
      const int col0 = colBase + wn * 64 + n * 16 + kg * 4;
      ushort4 o;
      o.x = f2bf(fmaxf(acc[mm][n][0] + bias[col0 + 0], 0.f));
      o.y = f2bf(fmaxf(acc[mm][n][1] + bias[col0 + 1], 0.f));
      o.z = f2bf(fmaxf(acc[mm][n][2] + bias[col0 + 2], 0.f));
      o.w = f2bf(fmaxf(acc[mm][n][3] + bias[col0 + 3], 0.f));
      *reinterpret_cast<ushort4*>(&C[(size_t)row * N + col0]) = o;
    }
  }
}

// ---------------- gemm8: 3-buffer counted vmcnt + bn-fast swizzle
__global__ __launch_bounds__(512, 2) void gemm8(
    const u16* __restrict__ A, const u16* __restrict__ Wt,
    const float* __restrict__ bias, u16* __restrict__ C,
    int M, int N, int K, int gm) {
  extern __shared__ __align__(16) u16 lds[];
  const int tid  = threadIdx.x;
  const int w    = tid >> 6;
  const int lane = tid & 63;
  const int fr   = lane & 15;
  const int kg   = lane >> 4;
  const int wm   = w >> 2;
  const int wn   = w & 3;

  const int nwg = gridDim.x;
  const int q = nwg >> 3, r = nwg & 7;
  const int xcd = blockIdx.x & 7, lid = blockIdx.x >> 3;
  const int swz = (xcd < r) ? (xcd * (q + 1) + lid) : (r * (q + 1) + (xcd - r) * q + lid);
  const int gn = N >> 8;
  const int bn = swz % gn, bm = swz / gn;
  const int rowBase = bm * 256, colBase = bn * 256;

  const int srow  = lane >> 2;
  const int sslot = (lane & 3) ^ ((lane >> 3) & 3);
  const u16* Asrc0 = A  + (size_t)(rowBase + w * 16 + srow) * K + sslot * 8;
  const u16* Bsrc0 = Wt + (size_t)(colBase + w * 16 + srow) * K + sslot * 8;
  const size_t rstep = (size_t)128 * K;

  const int NT = K / 32;

  f32x4 acc[8][4];
#pragma unroll
  for (int m = 0; m < 8; ++m)
#pragma unroll
    for (int n = 0; n < 4; ++n)
      acc[m][n] = f32x4{0.f, 0.f, 0.f, 0.f};

  const int aslot8 = (kg ^ ((fr >> 1) & 3)) * 8;
  const int ardA = (wm * 128 + fr) * 32 + aslot8;
  const int ardB = (wn * 64 + fr) * 32 + aslot8 + 8192;

  auto stage = [&](const u16* src0, int ldsElemBase, int kt) {
    const u16* s = src0 + (size_t)kt * 32;
    gload16(s,         &lds[ldsElemBase + w * 512]);
    gload16(s + rstep, &lds[ldsElemBase + w * 512 + 4096]);
  };

  stage(Asrc0, 0 * TILE_ELE,        0);
  stage(Bsrc0, 0 * TILE_ELE + 8192, 0);
  stage(Asrc0, 1 * TILE_ELE,        1);
  stage(Bsrc0, 1 * TILE_ELE + 8192, 1);

  for (int t = 0; t < NT; ++t) {
    const int cb = t % 3;
    const int sb = (t + 2) % 3;
    const bool dost = (t + 2) < NT;
    const int cA = cb * TILE_ELE;

    __builtin_amdgcn_sched_barrier(0);
    if (t < NT - 1) asm volatile("s_waitcnt vmcnt(4)" ::: "memory");
    else            asm volatile("s_waitcnt vmcnt(0)" ::: "memory");
    __builtin_amdgcn_s_barrier();
    __builtin_amdgcn_sched_barrier(0);

    bf16x8 a0 = *(const bf16x8*)&lds[cA + ardA + 0 * 512];
    bf16x8 a1 = *(const bf16x8*)&lds[cA + ardA + 1 * 512];
    bf16x8 a2 = *(const bf16x8*)&lds[cA + ardA + 2 * 512];
    bf16x8 a3 = *(const bf16x8*)&lds[cA + ardA + 3 * 512];
    bf16x8 b0 = *(const bf16x8*)&lds[cA + ardB + 0 * 512];
    bf16x8 b1 = *(const bf16x8*)&lds[cA + ardB + 1 * 512];
    bf16x8 b2 = *(const bf16x8*)&lds[cA + ardB + 2 * 512];
    bf16x8 b3 = *(const bf16x8*)&lds[cA + ardB + 3 * 512];
    bf16x8 c0 = *(const bf16x8*)&lds[cA + ardA + 2048 + 0 * 512];
    bf16x8 c1 = *(const bf16x8*)&lds[cA + ardA + 2048 + 1 * 512];
    bf16x8 c2 = *(const bf16x8*)&lds[cA + ardA + 2048 + 2 * 512];
    bf16x8 c3 = *(const bf16x8*)&lds[cA + ardA + 2048 + 3 * 512];
    if (dost) {
      stage(Asrc0, sb * TILE_ELE,        t + 2);
      stage(Bsrc0, sb * TILE_ELE + 8192, t + 2);
    }
#pragma unroll
    for (int n = 0; n < 4; ++n) {
      bf16x8 bf = (n == 0) ? b0 : (n == 1) ? b1 : (n == 2) ? b2 : b3;
      acc[0][n] = __builtin_amdgcn_mfma_f32_16x16x32_bf16(bf, a0, acc[0][n], 0, 0, 0);
      acc[1][n] = __builtin_amdgcn_mfma_f32_16x16x32_bf16(bf, a1, acc[1][n], 0, 0, 0);
      acc[2][n] = __builtin_amdgcn_mfma_f32_16x16x32_bf16(bf, a2, acc[2][n], 0, 0, 0);
      acc[3][n] = __builtin_amdgcn_mfma_f32_16x16x32_bf16(bf, a3, acc[3][n], 0, 0, 0);
      acc[4][n] = __builtin_amdgcn_mfma_f32_16x16x32_bf16(bf, c0, acc[4][n], 0, 0, 0);
      acc[5][n] = __builtin_amdgcn_mfma_f32_16x16x32_bf16(bf, c1, acc[5][n], 0, 0, 0);
      acc[6][n] = __builtin_amdgcn_mfma_f32_16x16x32_bf16(bf, c2, acc[6][n], 0, 0, 0);
      acc[7][n] = __builtin_amdgcn_mfma_f32_16x16x32_bf16(bf, c3, acc[7][n], 0, 0, 0);
    }
  }

#pragma unroll
  for (int mm = 0; mm < 8; ++mm) {
    const int row = rowBase + wm * 128 + (mm >> 2) * 64 + (mm & 3) * 16 + fr;
#pragma unroll
    for (int n = 0; n < 4; ++n) {
      const int col0 = colBase + wn * 64 + n * 16 + kg * 4;
      ushort4 o;
      o.x = f2bf(fmaxf(acc[mm][n][0] + bias[col0 + 0], 0.f));
      o.y = f2bf(fmaxf(acc[mm][n][1] + bias[col0 + 1], 0.f));
      o.z = f2bf(fmaxf(acc[mm][n][2] + bias[col0 + 2], 0.f));
      o.w = f2bf(fmaxf(acc[mm][n][3] + bias[col0 + 3], 0.f));
      *reinterpret_cast<ushort4*>(&C[(size_t)row * N + col0]) = o;
    }
  }
}

// ---------------- gemm3f: fused GEMM3 (128x256 tile, K=512) + W4 GEMV + softmax
__global__ __launch_bounds__(512, 2) void gemm3f(
    const u16* __restrict__ A, const u16* __restrict__ Wt,
    const float* __restrict__ bias, const float* __restrict__ W4,
    const float* __restrict__ b4, float* __restrict__ out, int gm) {
  constexpr int K = 512, NT = 16;
  __shared__ __align__(16) u16 lds[2][12288];
  __shared__ float w4s[512];
  __shared__ float zred[4][128][2];
  const int tid  = threadIdx.x;
  const int w    = tid >> 6;
  const int lane = tid & 63;
  const int fr   = lane & 15;
  const int kg   = lane >> 4;
  const int wm   = w >> 2;
  const int wn   = w & 3;

  const int nwg = gridDim.x;
  const int q = nwg >> 3, r = nwg & 7;
  const int xcd = blockIdx.x & 7, lid = blockIdx.x >> 3;
  const int swz = (xcd < r) ? (xcd * (q + 1) + lid) : (r * (q + 1) + (xcd - r) * q + lid);
  const int rowBase = swz * 128;

  if (tid < 512) w4s[tid] = W4[tid];

  const int xslot = (tid & 3) ^ ((tid >> 3) & 3);
  const u16* Asrc  = A  + (size_t)(rowBase + (tid >> 2)) * K + xslot * 8;
  const u16* Bsrc0 = Wt + (size_t)(tid >> 2) * K + xslot * 8;
  const u16* Bsrc1 = Wt + (size_t)((tid >> 2) + 128) * K + xslot * 8;

  auto stage = [&](int buf, int kt) {
    const int ko = kt * 32;
    gload16(Asrc  + ko, &lds[buf][tid * 8]);
    gload16(Bsrc0 + ko, &lds[buf][4096 + tid * 8]);
    gload16(Bsrc1 + ko, &lds[buf][8192 + tid * 8]);
  };

  f32x4 acc[4][4];
#pragma unroll
  for (int m = 0; m < 4; ++m)
#pragma unroll
    for (int n = 0; n < 4; ++n)
      acc[m][n] = f32x4{0.f, 0.f, 0.f, 0.f};

  const int aslot8 = (kg ^ ((fr >> 1) & 3)) * 8;
  const int ardA = (wm * 64 + fr) * 32 + aslot8;
  const int ardB = 4096 + (wn * 64 + fr) * 32 + aslot8;

  stage(0, 0);
  stage(1, 1);

  for (int t = 0; t < NT; ++t) {
    const int cb = t & 1;
    if (t < NT - 1) asm volatile("s_waitcnt vmcnt(3)" ::: "memory");
    else            asm volatile("s_waitcnt vmcnt(0)" ::: "memory");
    __builtin_amdgcn_s_barrier();

    bf16x8 a0 = *(const bf16x8*)&lds[cb][ardA + 0 * 512];
    bf16x8 a1 = *(const bf16x8*)&lds[cb][ardA + 1 * 512];
    bf16x8 a2 = *(const bf16x8*)&lds[cb][ardA + 2 * 512];
    bf16x8 a3 = *(const bf16x8*)&lds[cb][ardA + 3 * 512];
    bf16x8 b0 = *(const bf16x8*)&lds[cb][ardB + 0 * 512];
    bf16x8 b1 = *(const bf16x8*)&lds[cb][ardB + 1 * 512];
    bf16x8 b2 = *(const bf16x8*)&lds[cb][ardB + 2 * 512];
    bf16x8 b3 = *(const bf16x8*)&lds[cb][ardB + 3 * 512];
    asm volatile("s_waitcnt lgkmcnt(0)" ::: "memory");
    __builtin_amdgcn_s_barrier();
    if (t + 2 < NT) stage(cb, t + 2);
    __builtin_amdgcn_sched_barrier(0);
    __builtin_amdgcn_s_setprio(1);
#pragma unroll
    for (int n = 0; n < 4; ++n) {
      bf16x8 bf = (n == 0) ? b0 : (n == 1) ? b1 : (n == 2) ? b2 : b3;
      acc[0][n] = __builtin_amdgcn_mfma_f32_16x16x32_bf16(bf, a0, acc[0][n], 0, 0, 0);
      acc[1][n] = __builtin_amdgcn_mfma_f32_16x16x32_bf16(bf, a1, acc[1][n], 0, 0, 0);
      acc[2][n] = __builtin_amdgcn_mfma_f32_16x16x32_bf16(bf, a2, acc[2][n], 0, 0, 0);
      acc[3][n] = __builtin_amdgcn_mfma_f32_16x16x32_bf16(bf, a3, acc[3][n], 0, 0, 0);
    }
    __builtin_amdgcn_s_setprio(0);
  }

  float z0[4] = {0.f, 0.f, 0.f, 0.f};
  float z1[4] = {0.f, 0.f, 0.f, 0.f};
#pragma unroll
  for (int n = 0; n < 4; ++n) {
    const int col0 = wn * 64 + n * 16 + kg * 4;
#pragma unroll
    for (int j = 0; j < 4; ++j) {
      const int c = col0 + j;
      const float bv = bias[c];
      const float w40 = w4s[c * 2];
      const float w41 = w4s[c * 2 + 1];
#pragma unroll
      for (int m = 0; m < 4; ++m) {
        const float h = fmaxf(acc[m][n][j] + bv, 0.f);
        z0[m] += h * w40;
        z1[m] += h * w41;
      }
    }
  }
#pragma unroll
  for (int m = 0; m < 4; ++m) {
    z0[m] += __shfl_xor(z0[m], 16); z0[m] += __shfl_xor(z0[m], 32);
    z1[m] += __shfl_xor(z1[m], 16); z1[m] += __shfl_xor(z1[m], 32);
  }
  if (kg == 0) {
#pragma unroll
    for (int m = 0; m < 4; ++m) {
      const int rr = wm * 64 + m * 16 + fr;
      zred[wn][rr][0] = z0[m];
      zred[wn][rr][1] = z1[m];
    }
  }
  __syncthreads();
  if (tid < 128) {
    const float s0 = zred[0][tid][0] + zred[1][tid][0] + zred[2][tid][0] + zred[3][tid][0];
    const float s1 = zred[0][tid][1] + zred[1][tid][1] + zred[2][tid][1] + zred[3][tid][1];
    const float zz0 = fmaxf(s0 + b4[0], 0.f);
    const float zz1 = fmaxf(s1 + b4[1], 0.f);
    const float mx = fmaxf(zz0, zz1);
    const float e0 = __expf(zz0 - mx), e1 = __expf(zz1 - mx);
    const float inv = 1.0f / (e0 + e1);
    out[(size_t)(rowBase + tid) * 2]     = e0 * inv;
    out[(size_t)(rowBase + tid) * 2 + 1] = e1 * inv;
  }
}

// ---------------- host side
extern "C" void kernel_launch(void* const* d_in, const int* in_sizes, int n_in,
                              void* d_out, int out_size, void* d_ws, size_t ws_size,
                              hipStream_t stream) {
  const float* W1 = (const float*)d_in[32];
  const float* b1 = (const float*)d_in[33];
  const float* W2 = (const float*)d_in[34];
  const float* b2 = (const float*)d_in[35];
  const float* W3 = (const float*)d_in[36];
  const float* b3 = (const float*)d_in[37];
  const float* W4 = (const float*)d_in[38];
  const float* b4 = (const float*)d_in[39];

  (void)hipFuncSetAttribute(reinterpret_cast<const void*>(&gemm8),
                            hipFuncAttributeMaxDynamicSharedMemorySize, 98304);
  (void)hipFuncSetAttribute(reinterpret_cast<const void*>(&gemm1g),
                            hipFuncAttributeMaxDynamicSharedMemorySize, 118784);

  char* ws = (char*)d_ws;
  size_t off = 0;
  auto alloc = [&](size_t bytes) -> void* {
    void* p = ws + off;
    off += (bytes + 255) & ~(size_t)255;
    return p;
  };

  u16* W1t = (u16*)alloc((size_t)1024 * KPAD1 * 2);
  u16* W2t = (u16*)alloc((size_t)512 * 1024 * 2);
  u16* W3t = (u16*)alloc((size_t)256 * 512 * 2);
  u16* ebf = (u16*)alloc((size_t)EBF_TOTAL * 2);
  const size_t fixed = off;

  // per-chunk: P (Bc x 128) + H1 (Bc x 1024) + H2 (Bc x 512), bf16
  int nc = 64;
  const int cands[7] = {1, 2, 4, 8, 16, 32, 64};
  for (int ci = 0; ci < 7; ++ci) {
    size_t Bc = (size_t)B_TOTAL / cands[ci];
    size_t need = fixed + Bc * (128 + 1024 + 512) * 2 + 4096;
    if (need <= ws_size) { nc = cands[ci]; break; }
  }
  const int Bc = B_TOTAL / nc;

  u16* P  = (u16*)alloc((size_t)Bc * 128 * 2);
  u16* H1 = (u16*)alloc((size_t)Bc * 1024 * 2);
  u16* H2 = (u16*)alloc((size_t)Bc * 512 * 2);

  // tiled-transpose weight prep (coalesced reads AND writes)
  wprepT_kernel<<<dim3(KPAD1 / 32, 1024 / 32), 256, 0, stream>>>(W1, W1t, 1424, 1024, KPAD1);
  wprepT_kernel<<<dim3(1024 / 32, 512 / 32), 256, 0, stream>>>(W2, W2t, 1024, 512, 1024);
  wprepT_kernel<<<dim3(512 / 32, 256 / 32), 256, 0, stream>>>(W3, W3t, 512, 256, 512);

  EcvtArgs ea;
  for (int f = 0; f < 15; ++f) ea.E[f] = (const float*)d_in[2 * f + 1];
  ecvt_kernel<<<(EBF_TOTAL + 255) / 256, 256, 0, stream>>>(ea, ebf);

  G1Args g1;
  for (int f = 0; f < 15; ++f) g1.idx[f] = (const int*)d_in[2 * f];
  const int* idx_u = (const int*)d_in[30];
  const float* E_u = (const float*)d_in[31];

  const int gm = Bc / 256;
  for (int c = 0; c < nc; ++c) {
    G1Args g1c = g1;
    for (int f = 0; f < 15; ++f) g1c.idx[f] = g1.idx[f] + c * Bc;
    pool_kernel<<<Bc / 16, 512, 0, stream>>>(idx_u, E_u, P, c * Bc);
    gemm1g<<<gm * (1024 / 256), 512, 118784, stream>>>(g1c, ebf, P, W1t, b1, H1, 1024, gm);
    gemm8<<<gm * (512 / 256), 512, 98304, stream>>>(H1, W2t, b2, H2, Bc, 512, 1024, gm);
    gemm3f<<<Bc / 128, 512, 0, stream>>>(H2, W3t, b3, W4, b4,
                                         (float*)d_out + (size_t)c * Bc * 2, Bc / 128);
  }
}